// Round 6
// baseline (556.188 us; speedup 1.0000x reference)
//
#include <hip/hip_runtime.h>
#include <hip/hip_bf16.h>

// CellAnnotator R6: single-pass FP16 MFMA everywhere (error model: bf16-single=0.156 [R2],
// bf16-pair=0.031 [R4] => err ~ 64*2^-mant + 0.031 => fp16-single ~ 0.047 < 0.136 threshold).
//   K1 att: per 8x8 tile out[64px,64ch] = M[64,256]@X[256,64], fp16 frags, ONE pass,
//           2 barriers/tile, conflict-free M-scatter mapping. att stored f32.
//   K2 mlp: persistent, fp16 single-plane weights/acts, 8 MFMA/layer, LN in f32.

#define HH 768
#define WW 768
#define HWPX (HH*WW)

typedef __attribute__((ext_vector_type(8))) short short8;
typedef __attribute__((ext_vector_type(8))) _Float16 half8;
typedef __attribute__((ext_vector_type(4))) float f32x4;

union hcvt { _Float16 h; ushort u; };
__device__ __forceinline__ ushort f2h(float f) { hcvt c; c.h = (_Float16)f; return c.u; }
__device__ __forceinline__ float sigmoidf(float v) { return 1.f / (1.f + __expf(-v)); }

// Row pitch 256 ushorts (512B). XOR-swizzle low-3 bits of the 8-elem group index by row&7:
// bijective over 32 groups; frag reads ~2-way (free); scatter writes ~conflict-free with
// the p=(w*16+l15) mapping (enumerated: 16 lanes -> 16 distinct banks).
__device__ __forceinline__ int goff(int row, int g) {
  return (row << 8) + (((g & ~7) | ((g ^ row) & 7)) << 3);
}
__device__ __forceinline__ int eoff(int row, int k) {
  const int g = k >> 3;
  return (row << 8) + (((g & ~7) | ((g ^ row) & 7)) << 3) + (k & 7);
}

// ---------------- K1: att ----------------
__global__ __launch_bounds__(256, 2)
void att_k1(const float* __restrict__ x, float* __restrict__ attf) {
  __shared__ __align__(16) ushort Mb[64 * 256];   // 32 KB  M[px][k] fp16
  __shared__ __align__(16) ushort Xb[64 * 256];   // 32 KB  X^T[ch][k] fp16
  const int tid = threadIdx.x;
  const int lane = tid & 63, w = tid >> 6;
  const int l15 = lane & 15, lg = lane >> 4;

  // one-time zero: all of M (scatter slot-set is tile-invariant) + X k-groups 30,31
  {
    const short8 z8 = {0,0,0,0,0,0,0,0};
    #pragma unroll
    for (int i = 0; i < 8; ++i)
      *reinterpret_cast<short8*>(&Mb[(tid + i * 256) * 8]) = z8;
    if (tid < 128) {
      const int row = tid >> 1, g = 30 + (tid & 1);
      *reinterpret_cast<short8*>(&Xb[goff(row, g)]) = z8;
    }
  }

  const int b = blockIdx.x;
  const int tbase = (b & 7) * 1152 + (b >> 3) * 18;   // XCD-chunked tile bands
  const int p  = w * 16 + l15;             // scatter pixel (conflict-free mapping)
  const int pr = p >> 3, pc = p & 7;
  const int cb = lg << 4;                  // 16 channels of pixel p
  const int arow = w * 16 + l15;           // A-frag row

  for (int t18 = 0; t18 < 18; ++t18) {
    const int tile = tbase + t18;
    const int ti = (tile / 96) * 8, tj = (tile % 96) * 8;

    __syncthreads();                       // S0: prev tile's LDS reads done

    // center loads + sigmoid -> fp16 scatter into M
    {
      const float* cp = x + ((size_t)((ti + pr) * WW + (tj + pc)) << 6) + cb;
      #pragma unroll
      for (int qd = 0; qd < 4; ++qd) {
        const float4 v = *reinterpret_cast<const float4*>(cp + qd * 4);
        const float vs[4] = {v.x, v.y, v.z, v.w};
        #pragma unroll
        for (int j = 0; j < 4; ++j) {
          const int ch = cb + qd * 4 + j;
          const int k = ((pr + (ch >> 3)) << 4) | (pc + (ch & 7));
          Mb[eoff(p, k)] = f2h(sigmoidf(vs[j]));
        }
      }
    }
    // stage X^T fp16 (lane = channel; 8 halo px per k-group; coalesced 256B loads)
    #pragma unroll
    for (int t = 0; t < 8; ++t) {
      const int g = w + 4 * t;             // waves 2,3 skip g=30,31
      if (g < 30) {
        const int r = g >> 1, c0 = (g & 1) << 3;
        const int gr = ti + r - 3;
        const bool rok = (unsigned)gr < (unsigned)HH;
        float vv[8];
        #pragma unroll
        for (int s = 0; s < 8; ++s) {
          const int c = c0 + s;
          const int gc = tj + c - 3;
          vv[s] = (rok && c < 15 && (unsigned)gc < (unsigned)WW)
                      ? x[((size_t)(gr * WW + gc) << 6) + lane] : 0.f;
        }
        short8 h8;
        #pragma unroll
        for (int s = 0; s < 8; ++s) h8[s] = (short)f2h(vv[s]);
        *reinterpret_cast<short8*>(&Xb[goff(lane, g)]) = h8;
      }
    }
    __syncthreads();                       // S1: M + X visible

    // single GEMM pass: M @ X  (8 k-steps x 4 col-blocks)
    f32x4 acc[4];
    #pragma unroll
    for (int nb = 0; nb < 4; ++nb) acc[nb] = {0.f, 0.f, 0.f, 0.f};
    #pragma unroll
    for (int ks = 0; ks < 8; ++ks) {
      const int g = ks * 4 + lg;
      const half8 a = *reinterpret_cast<const half8*>(&Mb[goff(arow, g)]);
      #pragma unroll
      for (int nb = 0; nb < 4; ++nb) {
        const half8 bb = *reinterpret_cast<const half8*>(&Xb[goff(nb * 16 + l15, g)]);
        acc[nb] = __builtin_amdgcn_mfma_f32_16x16x32_f16(a, bb, acc[nb], 0, 0, 0);
      }
    }

    // store att f32 (4B element keeps K2's in-place alias discipline byte-exact)
    #pragma unroll
    for (int reg = 0; reg < 4; ++reg) {
      const int pl = w * 16 + lg * 4 + reg;
      const size_t gpx = (size_t)(ti + (pl >> 3)) * WW + (tj + (pl & 7));
      #pragma unroll
      for (int nb = 0; nb < 4; ++nb)
        attf[(gpx << 6) + nb * 16 + l15] = acc[nb][reg];
    }
  }
}

// ---------------- K2: MLP + LN + head (persistent, 512 threads, fp16 single) ----------------
__global__ __launch_bounds__(512, 4)
void mlp_k2(const float* attf, const float* __restrict__ Ws,
            const float* __restrict__ bs, const float* __restrict__ lns,
            const float* __restrict__ lnb, const float* __restrict__ w_out,
            const float* __restrict__ b_out, float* x0_out,
            float* __restrict__ out1) {
  __shared__ __align__(16) ushort wt[4 * 64 * 64];   // 32 KB [layer][co][ci swz] fp16
  __shared__ __align__(16) ushort act[8 * 1152];     // 18 KB wave-private act fp16
  const int tid = threadIdx.x;
  const int lane = tid & 63, wid = tid >> 6;
  const int l15 = lane & 15, lg = lane >> 4;

  // stage wt fp16 (thread = half a (layer,co) row)
  {
    const int row = tid >> 1;              // (layer<<6)|co
    const int l = row >> 6, co = row & 63;
    const int ci0 = (tid & 1) << 5;
    const int base = row << 6;
    for (int q = 0; q < 32; ++q) {
      const int ci = ci0 + q;
      const float v = Ws[(((l << 6) + ci) << 6) + co];
      const int e = ((((ci >> 3) ^ co) & 7) << 3) | (ci & 7);
      wt[base + e] = f2h(v);
    }
  }
  // hoist per-lane params
  float bias[4][4], sc[4][4], lbv[4][4];
  #pragma unroll
  for (int L = 0; L < 4; ++L)
    #pragma unroll
    for (int nb = 0; nb < 4; ++nb) {
      const int ch = (L << 6) + nb * 16 + l15;
      bias[L][nb] = bs[ch]; sc[L][nb] = lns[ch]; lbv[L][nb] = lnb[ch];
    }
  float wo[4];
  #pragma unroll
  for (int nb = 0; nb < 4; ++nb) wo[nb] = w_out[nb * 16 + l15];
  const float b0s = b_out[0];
  __syncthreads();

  ushort* const acth = act + wid * 1152;   // [16][72]

  for (int it = 0; it < 18; ++it) {
    const int chunk = blockIdx.x + (it << 8);      // 256 blocks x 18 iters
    const int px_base = chunk * 128 + wid * 16;

    // layer-0 A-frags from f32 att (block reads its own pixels before writing them)
    half8 a0, a1;
    {
      const float* ap = attf + ((size_t)(px_base + l15) << 6) + lg * 8;
      const float4 f0 = *reinterpret_cast<const float4*>(ap);
      const float4 f1 = *reinterpret_cast<const float4*>(ap + 4);
      const float4 f2 = *reinterpret_cast<const float4*>(ap + 32);
      const float4 f3 = *reinterpret_cast<const float4*>(ap + 36);
      a0[0]=(_Float16)f0.x; a0[1]=(_Float16)f0.y; a0[2]=(_Float16)f0.z; a0[3]=(_Float16)f0.w;
      a0[4]=(_Float16)f1.x; a0[5]=(_Float16)f1.y; a0[6]=(_Float16)f1.z; a0[7]=(_Float16)f1.w;
      a1[0]=(_Float16)f2.x; a1[1]=(_Float16)f2.y; a1[2]=(_Float16)f2.z; a1[3]=(_Float16)f2.w;
      a1[4]=(_Float16)f3.x; a1[5]=(_Float16)f3.y; a1[6]=(_Float16)f3.z; a1[7]=(_Float16)f3.w;
    }

    float y[4][4];
    #pragma unroll
    for (int layer = 0; layer < 4; ++layer) {
      if (layer > 0) {
        a0 = *reinterpret_cast<const half8*>(&acth[l15 * 72 + lg * 8]);
        a1 = *reinterpret_cast<const half8*>(&acth[l15 * 72 + 32 + lg * 8]);
      }
      f32x4 z[4];
      #pragma unroll
      for (int nb = 0; nb < 4; ++nb) {
        const int co = nb * 16 + l15;
        const int wb = ((layer << 6) + co) << 6;
        const int e0 = (((lg    ) ^ co) & 7) << 3;
        const int e1 = (((lg + 4) ^ co) & 7) << 3;
        const half8 b0 = *reinterpret_cast<const half8*>(&wt[wb + e0]);
        const half8 b1 = *reinterpret_cast<const half8*>(&wt[wb + e1]);
        z[nb] = {0.f, 0.f, 0.f, 0.f};
        z[nb] = __builtin_amdgcn_mfma_f32_16x16x32_f16(a0, b0, z[nb], 0, 0, 0);
        z[nb] = __builtin_amdgcn_mfma_f32_16x16x32_f16(a1, b1, z[nb], 0, 0, 0);
      }
      // bias + relu + LayerNorm
      #pragma unroll
      for (int reg = 0; reg < 4; ++reg) {
        float s = 0.f, ss = 0.f;
        #pragma unroll
        for (int nb = 0; nb < 4; ++nb) {
          float v = z[nb][reg] + bias[layer][nb];
          v = fmaxf(v, 0.f);
          y[reg][nb] = v;
          s += v; ss += v * v;
        }
        #pragma unroll
        for (int m = 1; m <= 8; m <<= 1) { s += __shfl_xor(s, m, 64); ss += __shfl_xor(ss, m, 64); }
        const float mu = s * 0.015625f;
        const float var = ss * 0.015625f - mu * mu;
        const float rstd = rsqrtf(var + 1e-6f);
        #pragma unroll
        for (int nb = 0; nb < 4; ++nb)
          y[reg][nb] = (y[reg][nb] - mu) * rstd * sc[layer][nb] + lbv[layer][nb];
      }
      if (layer < 3) {
        #pragma unroll
        for (int reg = 0; reg < 4; ++reg) {
          const int row = lg * 4 + reg;
          #pragma unroll
          for (int nb = 0; nb < 4; ++nb)
            acth[row * 72 + nb * 16 + l15] = f2h(y[reg][nb]);
        }
      }
    }

    // final stores: x0 f32 (overwrites this block's own att slots) + head
    #pragma unroll
    for (int reg = 0; reg < 4; ++reg) {
      const size_t pxg = (size_t)px_base + lg * 4 + reg;
      #pragma unroll
      for (int nb = 0; nb < 4; ++nb)
        x0_out[(pxg << 6) + nb * 16 + l15] = y[reg][nb];
      float part = y[reg][0] * wo[0] + y[reg][1] * wo[1] + y[reg][2] * wo[2] + y[reg][3] * wo[3];
      #pragma unroll
      for (int m = 1; m <= 8; m <<= 1) part += __shfl_xor(part, m, 64);
      if (l15 == 0) out1[pxg] = part + b0s;
    }
  }
}

extern "C" void kernel_launch(void* const* d_in, const int* in_sizes, int n_in,
                              void* d_out, int out_size, void* d_ws, size_t ws_size,
                              hipStream_t stream) {
  const float* x     = (const float*)d_in[0];
  const float* Ws    = (const float*)d_in[1];
  const float* bs    = (const float*)d_in[2];
  const float* lns   = (const float*)d_in[3];
  const float* lnbv  = (const float*)d_in[4];
  const float* w_out = (const float*)d_in[5];
  const float* b_out = (const float*)d_in[6];
  float* x0_out = (float*)d_out;
  float* out1   = x0_out + (size_t)HWPX * 64;

  // att buffer: workspace if big enough, else in-place over the x0 region (f32 elements,
  // block-private read-before-write in K2 -> race-free; K1 rewrites every launch).
  float* attbuf = (ws_size >= (size_t)HWPX * 64 * sizeof(float))
                      ? (float*)d_ws : (float*)d_out;

  att_k1<<<512, 256, 0, stream>>>(x, attbuf);
  mlp_k2<<<256, 512, 0, stream>>>((const float*)attbuf, Ws, bs, lns, lnbv,
                                  w_out, b_out, x0_out, out1);
}

// Round 7
// 230.629 us; speedup vs baseline: 2.4116x; 2.4116x over previous
//
#include <hip/hip_runtime.h>
#include <hip/hip_bf16.h>

// CellAnnotator R7: fp16 single-pass MFMA (validated R6: absmax 0.03125), K1 restructured
// as a software pipeline: issue next tile's 80 global loads into REGISTERS right after S1,
// so they fly during the GEMM and the next S0 (T14 async-STAGE). R6 regression root-cause:
// staging loads interleaved with converts/ds_writes -> few outstanding loads -> HBM at 470GB/s.
//   K1 att: per 8x8 tile out[64px,64ch] = M[64,256]@X[256,64] fp16, 2 barriers/tile.
//   K2 mlp: persistent, fp16 weights/acts, 8 MFMA/layer, LN f32 (unchanged from R6).

#define HH 768
#define WW 768
#define HWPX (HH*WW)

typedef __attribute__((ext_vector_type(8))) short short8;
typedef __attribute__((ext_vector_type(8))) _Float16 half8;
typedef __attribute__((ext_vector_type(4))) float f32x4;

union hcvt { _Float16 h; ushort u; };
__device__ __forceinline__ ushort f2h(float f) { hcvt c; c.h = (_Float16)f; return c.u; }
__device__ __forceinline__ float sigmoidf(float v) { return 1.f / (1.f + __expf(-v)); }

// Row pitch 256 ushorts (512B). XOR-swizzle low-3 bits of the 8-elem group index by row&7:
// bijective over 32 groups; quarter-wave b128 frag reads land 2-way (free, m136).
__device__ __forceinline__ int goff(int row, int g) {
  return (row << 8) + (((g & ~7) | ((g ^ row) & 7)) << 3);
}
__device__ __forceinline__ int eoff(int row, int k) {
  const int g = k >> 3;
  return (row << 8) + (((g & ~7) | ((g ^ row) & 7)) << 3) + (k & 7);
}

// ---------------- K1: att ----------------
__global__ __launch_bounds__(256, 2)
void att_k1(const float* __restrict__ x, float* __restrict__ attf) {
  __shared__ __align__(16) ushort Mb[64 * 256];   // 32 KB  M[px][k] fp16
  __shared__ __align__(16) ushort Xb[64 * 256];   // 32 KB  X^T[ch][k] fp16
  const int tid = threadIdx.x;
  const int lane = tid & 63, w = tid >> 6;
  const int l15 = lane & 15, lg = lane >> 4;

  // one-time zero: all of M (scatter slot-set is tile-invariant) + X k-groups 30,31
  {
    const short8 z8 = {0,0,0,0,0,0,0,0};
    #pragma unroll
    for (int i = 0; i < 8; ++i)
      *reinterpret_cast<short8*>(&Mb[(tid + i * 256) * 8]) = z8;
    if (tid < 128) {
      const int row = tid >> 1, g = 30 + (tid & 1);
      *reinterpret_cast<short8*>(&Xb[goff(row, g)]) = z8;
    }
  }

  const int b = blockIdx.x;
  const int tbase = (b & 7) * 1152 + (b >> 3) * 18;   // XCD-chunked tile bands
  const int p  = w * 16 + l15;             // scatter pixel (2-way bank pattern, measured-ok)
  const int pr = p >> 3, pc = p & 7;
  const int cb = lg << 4;                  // 16 channels of pixel p
  const int arow = w * 16 + l15;           // A-frag row

  // pipeline registers: halo values (8 groups x 8) + center channel quads (4 x float4)
  float vvA[8][8];
  float4 cv[4];

  // pure-load phase: 64 halo dwords + 4 center float4, no consumers -> all in flight.
  // Addresses always clamped into the image; masking happens in the write phase.
  auto issue_loads = [&](int tile) {
    const int ti = (tile / 96) * 8, tj = (tile % 96) * 8;
    {
      const float* cp = x + ((size_t)((ti + pr) * WW + (tj + pc)) << 6) + cb;
      #pragma unroll
      for (int qd = 0; qd < 4; ++qd)
        cv[qd] = *reinterpret_cast<const float4*>(cp + qd * 4);
    }
    #pragma unroll
    for (int t = 0; t < 8; ++t) {
      const int g = w + 4 * t;
      const int r = g >> 1, c0 = (g & 1) << 3;
      const int gr = min(max(ti + r - 3, 0), HH - 1);
      const float* rowp = x + ((size_t)gr * WW << 6) + lane;
      #pragma unroll
      for (int s = 0; s < 8; ++s) {
        const int gc = min(max(tj + c0 + s - 3, 0), WW - 1);
        vvA[t][s] = rowp[(size_t)gc << 6];
      }
    }
  };

  // cvt + LDS-write phase (consumes the registers; masks OOB/pad to zero)
  auto write_lds = [&](int tile) {
    const int ti = (tile / 96) * 8, tj = (tile % 96) * 8;
    // M scatter: sigmoid(center) fp16
    #pragma unroll
    for (int qd = 0; qd < 4; ++qd) {
      const float vs[4] = {cv[qd].x, cv[qd].y, cv[qd].z, cv[qd].w};
      #pragma unroll
      for (int j = 0; j < 4; ++j) {
        const int ch = cb + qd * 4 + j;
        const int k = ((pr + (ch >> 3)) << 4) | (pc + (ch & 7));
        Mb[eoff(p, k)] = f2h(sigmoidf(vs[j]));
      }
    }
    // X^T rows (lane = channel)
    #pragma unroll
    for (int t = 0; t < 8; ++t) {
      const int g = w + 4 * t;
      if (g < 30) {
        const int r = g >> 1, c0 = (g & 1) << 3;
        const int gr = ti + r - 3;
        const bool rok = (unsigned)gr < (unsigned)HH;
        short8 h8;
        #pragma unroll
        for (int s = 0; s < 8; ++s) {
          const int c = c0 + s;
          const int gc = tj + c - 3;
          const bool ok = rok && (c < 15) && ((unsigned)gc < (unsigned)WW);
          h8[s] = (short)f2h(ok ? vvA[t][s] : 0.f);
        }
        *reinterpret_cast<short8*>(&Xb[goff(lane, g)]) = h8;
      }
    }
  };

  issue_loads(tbase);                      // prologue: tile 0 loads in flight

  for (int t18 = 0; t18 < 18; ++t18) {
    const int tile = tbase + t18;
    const int ti = (tile / 96) * 8, tj = (tile % 96) * 8;

    __syncthreads();                       // S0: prev tile's LDS reads done (or init writes)
    write_lds(tile);                       // waits vmcnt for this tile's regs
    __syncthreads();                       // S1: M + X visible

    if (t18 < 17) issue_loads(tile + 1);   // prefetch: flies during GEMM + next S0

    // single GEMM pass: M @ X  (8 k-steps x 4 col-blocks)
    f32x4 acc[4];
    #pragma unroll
    for (int nb = 0; nb < 4; ++nb) acc[nb] = {0.f, 0.f, 0.f, 0.f};
    #pragma unroll
    for (int ks = 0; ks < 8; ++ks) {
      const int g = ks * 4 + lg;
      const half8 a = *reinterpret_cast<const half8*>(&Mb[goff(arow, g)]);
      #pragma unroll
      for (int nb = 0; nb < 4; ++nb) {
        const half8 bb = *reinterpret_cast<const half8*>(&Xb[goff(nb * 16 + l15, g)]);
        acc[nb] = __builtin_amdgcn_mfma_f32_16x16x32_f16(a, bb, acc[nb], 0, 0, 0);
      }
    }

    // store att f32 (4B element keeps K2's in-place alias discipline byte-exact)
    #pragma unroll
    for (int reg = 0; reg < 4; ++reg) {
      const int pl = w * 16 + lg * 4 + reg;
      const size_t gpx = (size_t)(ti + (pl >> 3)) * WW + (tj + (pl & 7));
      #pragma unroll
      for (int nb = 0; nb < 4; ++nb)
        attf[(gpx << 6) + nb * 16 + l15] = acc[nb][reg];
    }
  }
}

// ---------------- K2: MLP + LN + head (persistent, 512 threads, fp16) ----------------
__global__ __launch_bounds__(512, 4)
void mlp_k2(const float* attf, const float* __restrict__ Ws,
            const float* __restrict__ bs, const float* __restrict__ lns,
            const float* __restrict__ lnb, const float* __restrict__ w_out,
            const float* __restrict__ b_out, float* x0_out,
            float* __restrict__ out1) {
  __shared__ __align__(16) ushort wt[4 * 64 * 64];   // 32 KB [layer][co][ci swz] fp16
  __shared__ __align__(16) ushort act[8 * 1152];     // 18 KB wave-private act fp16
  const int tid = threadIdx.x;
  const int lane = tid & 63, wid = tid >> 6;
  const int l15 = lane & 15, lg = lane >> 4;

  // stage wt fp16 (thread = half a (layer,co) row)
  {
    const int row = tid >> 1;              // (layer<<6)|co
    const int l = row >> 6, co = row & 63;
    const int ci0 = (tid & 1) << 5;
    const int base = row << 6;
    for (int q = 0; q < 32; ++q) {
      const int ci = ci0 + q;
      const float v = Ws[(((l << 6) + ci) << 6) + co];
      const int e = ((((ci >> 3) ^ co) & 7) << 3) | (ci & 7);
      wt[base + e] = f2h(v);
    }
  }
  // hoist per-lane params
  float bias[4][4], sc[4][4], lbv[4][4];
  #pragma unroll
  for (int L = 0; L < 4; ++L)
    #pragma unroll
    for (int nb = 0; nb < 4; ++nb) {
      const int ch = (L << 6) + nb * 16 + l15;
      bias[L][nb] = bs[ch]; sc[L][nb] = lns[ch]; lbv[L][nb] = lnb[ch];
    }
  float wo[4];
  #pragma unroll
  for (int nb = 0; nb < 4; ++nb) wo[nb] = w_out[nb * 16 + l15];
  const float b0s = b_out[0];
  __syncthreads();

  ushort* const acth = act + wid * 1152;   // [16][72]

  for (int it = 0; it < 18; ++it) {
    const int chunk = blockIdx.x + (it << 8);      // 256 blocks x 18 iters
    const int px_base = chunk * 128 + wid * 16;

    // layer-0 A-frags from f32 att (block reads its own pixels before writing them)
    half8 a0, a1;
    {
      const float* ap = attf + ((size_t)(px_base + l15) << 6) + lg * 8;
      const float4 f0 = *reinterpret_cast<const float4*>(ap);
      const float4 f1 = *reinterpret_cast<const float4*>(ap + 4);
      const float4 f2 = *reinterpret_cast<const float4*>(ap + 32);
      const float4 f3 = *reinterpret_cast<const float4*>(ap + 36);
      a0[0]=(_Float16)f0.x; a0[1]=(_Float16)f0.y; a0[2]=(_Float16)f0.z; a0[3]=(_Float16)f0.w;
      a0[4]=(_Float16)f1.x; a0[5]=(_Float16)f1.y; a0[6]=(_Float16)f1.z; a0[7]=(_Float16)f1.w;
      a1[0]=(_Float16)f2.x; a1[1]=(_Float16)f2.y; a1[2]=(_Float16)f2.z; a1[3]=(_Float16)f2.w;
      a1[4]=(_Float16)f3.x; a1[5]=(_Float16)f3.y; a1[6]=(_Float16)f3.z; a1[7]=(_Float16)f3.w;
    }

    float y[4][4];
    #pragma unroll
    for (int layer = 0; layer < 4; ++layer) {
      if (layer > 0) {
        a0 = *reinterpret_cast<const half8*>(&acth[l15 * 72 + lg * 8]);
        a1 = *reinterpret_cast<const half8*>(&acth[l15 * 72 + 32 + lg * 8]);
      }
      f32x4 z[4];
      #pragma unroll
      for (int nb = 0; nb < 4; ++nb) {
        const int co = nb * 16 + l15;
        const int wb = ((layer << 6) + co) << 6;
        const int e0 = (((lg    ) ^ co) & 7) << 3;
        const int e1 = (((lg + 4) ^ co) & 7) << 3;
        const half8 b0 = *reinterpret_cast<const half8*>(&wt[wb + e0]);
        const half8 b1 = *reinterpret_cast<const half8*>(&wt[wb + e1]);
        z[nb] = {0.f, 0.f, 0.f, 0.f};
        z[nb] = __builtin_amdgcn_mfma_f32_16x16x32_f16(a0, b0, z[nb], 0, 0, 0);
        z[nb] = __builtin_amdgcn_mfma_f32_16x16x32_f16(a1, b1, z[nb], 0, 0, 0);
      }
      // bias + relu + LayerNorm
      #pragma unroll
      for (int reg = 0; reg < 4; ++reg) {
        float s = 0.f, ss = 0.f;
        #pragma unroll
        for (int nb = 0; nb < 4; ++nb) {
          float v = z[nb][reg] + bias[layer][nb];
          v = fmaxf(v, 0.f);
          y[reg][nb] = v;
          s += v; ss += v * v;
        }
        #pragma unroll
        for (int m = 1; m <= 8; m <<= 1) { s += __shfl_xor(s, m, 64); ss += __shfl_xor(ss, m, 64); }
        const float mu = s * 0.015625f;
        const float var = ss * 0.015625f - mu * mu;
        const float rstd = rsqrtf(var + 1e-6f);
        #pragma unroll
        for (int nb = 0; nb < 4; ++nb)
          y[reg][nb] = (y[reg][nb] - mu) * rstd * sc[layer][nb] + lbv[layer][nb];
      }
      if (layer < 3) {
        #pragma unroll
        for (int reg = 0; reg < 4; ++reg) {
          const int row = lg * 4 + reg;
          #pragma unroll
          for (int nb = 0; nb < 4; ++nb)
            acth[row * 72 + nb * 16 + l15] = f2h(y[reg][nb]);
        }
      }
    }

    // final stores: x0 f32 (overwrites this block's own att slots) + head
    #pragma unroll
    for (int reg = 0; reg < 4; ++reg) {
      const size_t pxg = (size_t)px_base + lg * 4 + reg;
      #pragma unroll
      for (int nb = 0; nb < 4; ++nb)
        x0_out[(pxg << 6) + nb * 16 + l15] = y[reg][nb];
      float part = y[reg][0] * wo[0] + y[reg][1] * wo[1] + y[reg][2] * wo[2] + y[reg][3] * wo[3];
      #pragma unroll
      for (int m = 1; m <= 8; m <<= 1) part += __shfl_xor(part, m, 64);
      if (l15 == 0) out1[pxg] = part + b0s;
    }
  }
}

extern "C" void kernel_launch(void* const* d_in, const int* in_sizes, int n_in,
                              void* d_out, int out_size, void* d_ws, size_t ws_size,
                              hipStream_t stream) {
  const float* x     = (const float*)d_in[0];
  const float* Ws    = (const float*)d_in[1];
  const float* bs    = (const float*)d_in[2];
  const float* lns   = (const float*)d_in[3];
  const float* lnbv  = (const float*)d_in[4];
  const float* w_out = (const float*)d_in[5];
  const float* b_out = (const float*)d_in[6];
  float* x0_out = (float*)d_out;
  float* out1   = x0_out + (size_t)HWPX * 64;

  // att buffer: workspace if big enough, else in-place over the x0 region (f32 elements,
  // block-private read-before-write in K2 -> race-free; K1 rewrites every launch).
  float* attbuf = (ws_size >= (size_t)HWPX * 64 * sizeof(float))
                      ? (float*)d_ws : (float*)d_out;

  att_k1<<<512, 256, 0, stream>>>(x, attbuf);
  mlp_k2<<<256, 512, 0, stream>>>((const float*)attbuf, Ws, bs, lns, lnbv,
                                  w_out, b_out, x0_out, out1);
}

// Round 8
// 222.298 us; speedup vs baseline: 2.5020x; 1.0375x over previous
//
#include <hip/hip_runtime.h>
#include <hip/hip_bf16.h>

// CellAnnotator R8: R7 + sliding-window halo reuse in K1.
// Bands advance 8 cols/tile; new left half of the 16-col halo window == old right half
// (masks match: ti band-constant, col range identical). Each wave owns whole halo rows
// (r == w mod 4), keeps packed right-half short8 in regs, loads only 8 new cols/row/tile.
// Band-start and band-wrap (tile%96==0) tiles restage fully.
//   K1 att: per 8x8 tile out[64px,64ch] = M[64,256]@X[256,64] fp16, 2 barriers/tile.
//   K2 mlp: persistent, fp16 weights/acts, 8 MFMA/layer, LN f32 (unchanged from R7).

#define HH 768
#define WW 768
#define HWPX (HH*WW)

typedef __attribute__((ext_vector_type(8))) short short8;
typedef __attribute__((ext_vector_type(8))) _Float16 half8;
typedef __attribute__((ext_vector_type(4))) float f32x4;

union hcvt { _Float16 h; ushort u; };
__device__ __forceinline__ ushort f2h(float f) { hcvt c; c.h = (_Float16)f; return c.u; }
__device__ __forceinline__ float sigmoidf(float v) { return 1.f / (1.f + __expf(-v)); }

// Row pitch 256 ushorts (512B). XOR-swizzle low-3 bits of the 8-elem group index by row&7:
// bijective over 32 groups; quarter-wave b128 frag reads land 2-way (free, m136).
__device__ __forceinline__ int goff(int row, int g) {
  return (row << 8) + (((g & ~7) | ((g ^ row) & 7)) << 3);
}
__device__ __forceinline__ int eoff(int row, int k) {
  const int g = k >> 3;
  return (row << 8) + (((g & ~7) | ((g ^ row) & 7)) << 3) + (k & 7);
}

// ---------------- K1: att ----------------
__global__ __launch_bounds__(256, 2)
void att_k1(const float* __restrict__ x, float* __restrict__ attf) {
  __shared__ __align__(16) ushort Mb[64 * 256];   // 32 KB  M[px][k] fp16
  __shared__ __align__(16) ushort Xb[64 * 256];   // 32 KB  X^T[ch][k] fp16
  const int tid = threadIdx.x;
  const int lane = tid & 63, w = tid >> 6;
  const int l15 = lane & 15, lg = lane >> 4;

  // one-time zero: all of M (scatter slot-set is tile-invariant) + X k-groups 30,31
  {
    const short8 z8 = {0,0,0,0,0,0,0,0};
    #pragma unroll
    for (int i = 0; i < 8; ++i)
      *reinterpret_cast<short8*>(&Mb[(tid + i * 256) * 8]) = z8;
    if (tid < 128) {
      const int row = tid >> 1, g = 30 + (tid & 1);
      *reinterpret_cast<short8*>(&Xb[goff(row, g)]) = z8;
    }
  }

  const int b = blockIdx.x;
  const int tbase = (b & 7) * 1152 + (b >> 3) * 18;   // XCD-chunked tile bands
  const int p  = w * 16 + l15;             // scatter pixel
  const int pr = p >> 3, pc = p & 7;
  const int cb = lg << 4;                  // 16 channels of pixel p
  const int arow = w * 16 + l15;           // A-frag row

  // pipeline registers
  float4 cv[4];                            // center channel quads
  float Rv[4][8];                          // new right-half halo cols (f32, pre-mask)
  float Lv[4][8];                          // left-half cols (fresh restage only)
  short8 rs[4];                            // packed right halves carried across tiles

  // pure-load phase (no consumers until after next barrier). Wave w owns halo rows
  // r = w + 4i (r<15). Addresses clamped; masking at write time.
  auto issue_loads = [&](int ti, int tj, bool fresh) {
    {
      const float* cp = x + ((size_t)((ti + pr) * WW + (tj + pc)) << 6) + cb;
      #pragma unroll
      for (int qd = 0; qd < 4; ++qd)
        cv[qd] = *reinterpret_cast<const float4*>(cp + qd * 4);
    }
    #pragma unroll
    for (int i = 0; i < 4; ++i) {
      const int r = w + 4 * i;
      if (r < 15) {
        const int gr = min(max(ti + r - 3, 0), HH - 1);
        const float* rowp = x + ((size_t)gr * WW << 6) + lane;
        #pragma unroll
        for (int s = 0; s < 8; ++s) {              // new right half: cols c=8..15
          const int gc = min(max(tj + 5 + s, 0), WW - 1);
          Rv[i][s] = rowp[(size_t)gc << 6];
        }
        if (fresh) {
          #pragma unroll
          for (int s = 0; s < 8; ++s) {            // left half: cols c=0..7
            const int gc = min(max(tj - 3 + s, 0), WW - 1);
            Lv[i][s] = rowp[(size_t)gc << 6];
          }
        }
      }
    }
  };

  // cvt + LDS-write phase (consumes registers; masks OOB to zero)
  auto write_lds = [&](int ti, int tj, bool fresh) {
    // M scatter: sigmoid(center) fp16
    #pragma unroll
    for (int qd = 0; qd < 4; ++qd) {
      const float vs[4] = {cv[qd].x, cv[qd].y, cv[qd].z, cv[qd].w};
      #pragma unroll
      for (int j = 0; j < 4; ++j) {
        const int ch = cb + qd * 4 + j;
        const int k = ((pr + (ch >> 3)) << 4) | (pc + (ch & 7));
        Mb[eoff(p, k)] = f2h(sigmoidf(vs[j]));
      }
    }
    // X^T rows (lane = channel): left8 = reused old right (or fresh pack), right8 = new
    #pragma unroll
    for (int i = 0; i < 4; ++i) {
      const int r = w + 4 * i;
      if (r < 15) {
        const int gr = ti + r - 3;
        const bool rok = (unsigned)gr < (unsigned)HH;
        short8 left8;
        if (fresh) {
          #pragma unroll
          for (int s = 0; s < 8; ++s) {
            const int j = tj - 3 + s;
            const bool ok = rok && ((unsigned)j < (unsigned)WW);
            left8[s] = (short)f2h(ok ? Lv[i][s] : 0.f);
          }
        } else {
          left8 = rs[i];                   // masks match: same ti, same global cols
        }
        short8 right8;
        #pragma unroll
        for (int s = 0; s < 8; ++s) {
          const int j = tj + 5 + s;
          const bool ok = rok && ((unsigned)j < (unsigned)WW);
          right8[s] = (short)f2h(ok ? Rv[i][s] : 0.f);
        }
        *reinterpret_cast<short8*>(&Xb[goff(lane, 2 * r)])     = left8;
        *reinterpret_cast<short8*>(&Xb[goff(lane, 2 * r + 1)]) = right8;
        rs[i] = right8;
      }
    }
  };

  // prologue: tile 0 (fresh) loads in flight
  {
    const int t0 = tbase;
    issue_loads((t0 / 96) * 8, (t0 % 96) * 8, true);
  }

  for (int t18 = 0; t18 < 18; ++t18) {
    const int tile = tbase + t18;
    const int ti = (tile / 96) * 8, tj = (tile % 96) * 8;
    const bool fresh = (t18 == 0) || (tj == 0);    // band start or band wrap

    __syncthreads();                       // S0: prev tile's LDS reads done (or init writes)
    write_lds(ti, tj, fresh);              // waits vmcnt for this tile's regs
    __syncthreads();                       // S1: M + X visible

    if (t18 < 17) {                        // prefetch next tile: flies during GEMM + S0
      const int nt = tile + 1;
      issue_loads((nt / 96) * 8, (nt % 96) * 8, (nt % 96) == 0);
    }

    // single GEMM pass: M @ X  (8 k-steps x 4 col-blocks)
    f32x4 acc[4];
    #pragma unroll
    for (int nb = 0; nb < 4; ++nb) acc[nb] = {0.f, 0.f, 0.f, 0.f};
    #pragma unroll
    for (int ks = 0; ks < 8; ++ks) {
      const int g = ks * 4 + lg;
      const half8 a = *reinterpret_cast<const half8*>(&Mb[goff(arow, g)]);
      #pragma unroll
      for (int nb = 0; nb < 4; ++nb) {
        const half8 bb = *reinterpret_cast<const half8*>(&Xb[goff(nb * 16 + l15, g)]);
        acc[nb] = __builtin_amdgcn_mfma_f32_16x16x32_f16(a, bb, acc[nb], 0, 0, 0);
      }
    }

    // store att f32 (4B element keeps K2's in-place alias discipline byte-exact)
    #pragma unroll
    for (int reg = 0; reg < 4; ++reg) {
      const int pl = w * 16 + lg * 4 + reg;
      const size_t gpx = (size_t)(ti + (pl >> 3)) * WW + (tj + (pl & 7));
      #pragma unroll
      for (int nb = 0; nb < 4; ++nb)
        attf[(gpx << 6) + nb * 16 + l15] = acc[nb][reg];
    }
  }
}

// ---------------- K2: MLP + LN + head (persistent, 512 threads, fp16) ----------------
__global__ __launch_bounds__(512, 4)
void mlp_k2(const float* attf, const float* __restrict__ Ws,
            const float* __restrict__ bs, const float* __restrict__ lns,
            const float* __restrict__ lnb, const float* __restrict__ w_out,
            const float* __restrict__ b_out, float* x0_out,
            float* __restrict__ out1) {
  __shared__ __align__(16) ushort wt[4 * 64 * 64];   // 32 KB [layer][co][ci swz] fp16
  __shared__ __align__(16) ushort act[8 * 1152];     // 18 KB wave-private act fp16
  const int tid = threadIdx.x;
  const int lane = tid & 63, wid = tid >> 6;
  const int l15 = lane & 15, lg = lane >> 4;

  // stage wt fp16 (thread = half a (layer,co) row)
  {
    const int row = tid >> 1;              // (layer<<6)|co
    const int l = row >> 6, co = row & 63;
    const int ci0 = (tid & 1) << 5;
    const int base = row << 6;
    for (int q = 0; q < 32; ++q) {
      const int ci = ci0 + q;
      const float v = Ws[(((l << 6) + ci) << 6) + co];
      const int e = ((((ci >> 3) ^ co) & 7) << 3) | (ci & 7);
      wt[base + e] = f2h(v);
    }
  }
  // hoist per-lane params
  float bias[4][4], sc[4][4], lbv[4][4];
  #pragma unroll
  for (int L = 0; L < 4; ++L)
    #pragma unroll
    for (int nb = 0; nb < 4; ++nb) {
      const int ch = (L << 6) + nb * 16 + l15;
      bias[L][nb] = bs[ch]; sc[L][nb] = lns[ch]; lbv[L][nb] = lnb[ch];
    }
  float wo[4];
  #pragma unroll
  for (int nb = 0; nb < 4; ++nb) wo[nb] = w_out[nb * 16 + l15];
  const float b0s = b_out[0];
  __syncthreads();

  ushort* const acth = act + wid * 1152;   // [16][72]

  for (int it = 0; it < 18; ++it) {
    const int chunk = blockIdx.x + (it << 8);      // 256 blocks x 18 iters
    const int px_base = chunk * 128 + wid * 16;

    // layer-0 A-frags from f32 att (block reads its own pixels before writing them)
    half8 a0, a1;
    {
      const float* ap = attf + ((size_t)(px_base + l15) << 6) + lg * 8;
      const float4 f0 = *reinterpret_cast<const float4*>(ap);
      const float4 f1 = *reinterpret_cast<const float4*>(ap + 4);
      const float4 f2 = *reinterpret_cast<const float4*>(ap + 32);
      const float4 f3 = *reinterpret_cast<const float4*>(ap + 36);
      a0[0]=(_Float16)f0.x; a0[1]=(_Float16)f0.y; a0[2]=(_Float16)f0.z; a0[3]=(_Float16)f0.w;
      a0[4]=(_Float16)f1.x; a0[5]=(_Float16)f1.y; a0[6]=(_Float16)f1.z; a0[7]=(_Float16)f1.w;
      a1[0]=(_Float16)f2.x; a1[1]=(_Float16)f2.y; a1[2]=(_Float16)f2.z; a1[3]=(_Float16)f2.w;
      a1[4]=(_Float16)f3.x; a1[5]=(_Float16)f3.y; a1[6]=(_Float16)f3.z; a1[7]=(_Float16)f3.w;
    }

    float y[4][4];
    #pragma unroll
    for (int layer = 0; layer < 4; ++layer) {
      if (layer > 0) {
        a0 = *reinterpret_cast<const half8*>(&acth[l15 * 72 + lg * 8]);
        a1 = *reinterpret_cast<const half8*>(&acth[l15 * 72 + 32 + lg * 8]);
      }
      f32x4 z[4];
      #pragma unroll
      for (int nb = 0; nb < 4; ++nb) {
        const int co = nb * 16 + l15;
        const int wb = ((layer << 6) + co) << 6;
        const int e0 = (((lg    ) ^ co) & 7) << 3;
        const int e1 = (((lg + 4) ^ co) & 7) << 3;
        const half8 b0 = *reinterpret_cast<const half8*>(&wt[wb + e0]);
        const half8 b1 = *reinterpret_cast<const half8*>(&wt[wb + e1]);
        z[nb] = {0.f, 0.f, 0.f, 0.f};
        z[nb] = __builtin_amdgcn_mfma_f32_16x16x32_f16(a0, b0, z[nb], 0, 0, 0);
        z[nb] = __builtin_amdgcn_mfma_f32_16x16x32_f16(a1, b1, z[nb], 0, 0, 0);
      }
      // bias + relu + LayerNorm
      #pragma unroll
      for (int reg = 0; reg < 4; ++reg) {
        float s = 0.f, ss = 0.f;
        #pragma unroll
        for (int nb = 0; nb < 4; ++nb) {
          float v = z[nb][reg] + bias[layer][nb];
          v = fmaxf(v, 0.f);
          y[reg][nb] = v;
          s += v; ss += v * v;
        }
        #pragma unroll
        for (int m = 1; m <= 8; m <<= 1) { s += __shfl_xor(s, m, 64); ss += __shfl_xor(ss, m, 64); }
        const float mu = s * 0.015625f;
        const float var = ss * 0.015625f - mu * mu;
        const float rstd = rsqrtf(var + 1e-6f);
        #pragma unroll
        for (int nb = 0; nb < 4; ++nb)
          y[reg][nb] = (y[reg][nb] - mu) * rstd * sc[layer][nb] + lbv[layer][nb];
      }
      if (layer < 3) {
        #pragma unroll
        for (int reg = 0; reg < 4; ++reg) {
          const int row = lg * 4 + reg;
          #pragma unroll
          for (int nb = 0; nb < 4; ++nb)
            acth[row * 72 + nb * 16 + l15] = f2h(y[reg][nb]);
        }
      }
    }

    // final stores: x0 f32 (overwrites this block's own att slots) + head
    #pragma unroll
    for (int reg = 0; reg < 4; ++reg) {
      const size_t pxg = (size_t)px_base + lg * 4 + reg;
      #pragma unroll
      for (int nb = 0; nb < 4; ++nb)
        x0_out[(pxg << 6) + nb * 16 + l15] = y[reg][nb];
      float part = y[reg][0] * wo[0] + y[reg][1] * wo[1] + y[reg][2] * wo[2] + y[reg][3] * wo[3];
      #pragma unroll
      for (int m = 1; m <= 8; m <<= 1) part += __shfl_xor(part, m, 64);
      if (l15 == 0) out1[pxg] = part + b0s;
    }
  }
}

extern "C" void kernel_launch(void* const* d_in, const int* in_sizes, int n_in,
                              void* d_out, int out_size, void* d_ws, size_t ws_size,
                              hipStream_t stream) {
  const float* x     = (const float*)d_in[0];
  const float* Ws    = (const float*)d_in[1];
  const float* bs    = (const float*)d_in[2];
  const float* lns   = (const float*)d_in[3];
  const float* lnbv  = (const float*)d_in[4];
  const float* w_out = (const float*)d_in[5];
  const float* b_out = (const float*)d_in[6];
  float* x0_out = (float*)d_out;
  float* out1   = x0_out + (size_t)HWPX * 64;

  // att buffer: workspace if big enough, else in-place over the x0 region (f32 elements,
  // block-private read-before-write in K2 -> race-free; K1 rewrites every launch).
  float* attbuf = (ws_size >= (size_t)HWPX * 64 * sizeof(float))
                      ? (float*)d_ws : (float*)d_out;

  att_k1<<<512, 256, 0, stream>>>(x, attbuf);
  mlp_k2<<<256, 512, 0, stream>>>((const float*)attbuf, Ws, bs, lns, lnbv,
                                  w_out, b_out, x0_out, out1);
}

// Round 9
// 195.734 us; speedup vs baseline: 2.8415x; 1.1357x over previous
//
#include <hip/hip_runtime.h>
#include <hip/hip_bf16.h>

// CellAnnotator R9: latency-chain fixes in K1.
//  - Phase rotation: S0 -> write_lds(t) -> S1 -> store(t-1) -> prefetch(t+1) -> GEMM(t).
//    Every barrier's implicit vmcnt(0) drain now only meets >=1-iteration-old VMEM ops
//    (R8 stalled ~800cy/tile draining just-issued att stores at S0).
//  - GEMM: mfma_f32_32x32x16_f16, K=240 (krows 0..14), 30 LDS reads + 15 MFMA per wave
//    (vs 40+32), 2 interleaved acc chains. A/B packed with the same slot->k map (any HW
//    k-permutation cancels); D-map: col=lane&31, row=(reg&3)+8*(reg>>2)+4*(lane>>5).
//  - att stored fp16 in ws (identical rounding to R8's f32-store+K2-convert); f32
//    in-place fallback kept via template.

#define HH 768
#define WW 768
#define HWPX (HH*WW)

typedef __attribute__((ext_vector_type(8))) short short8;
typedef __attribute__((ext_vector_type(8))) _Float16 half8;
typedef __attribute__((ext_vector_type(4))) float f32x4;
typedef __attribute__((ext_vector_type(16))) float f32x16;

union hcvt { _Float16 h; ushort u; };
__device__ __forceinline__ ushort f2h(float f) { hcvt c; c.h = (_Float16)f; return c.u; }
__device__ __forceinline__ float sigmoidf(float v) { return 1.f / (1.f + __expf(-v)); }

// Row pitch 256 ushorts (512B). XOR-swizzle low-3 bits of the 8-elem group index by row&7
// (bijective over 32 groups). GEMM touches only g<=29 (K=240); positions may swizzle into
// slots 30,31 -> in-row, fine.
__device__ __forceinline__ int goff(int row, int g) {
  return (row << 8) + (((g & ~7) | ((g ^ row) & 7)) << 3);
}
__device__ __forceinline__ int eoff(int row, int k) {
  const int g = k >> 3;
  return (row << 8) + (((g & ~7) | ((g ^ row) & 7)) << 3) + (k & 7);
}

// ---------------- K1: att ----------------
template<bool F16OUT>
__global__ __launch_bounds__(256, 2)
void att_k1(const float* __restrict__ x, void* __restrict__ attout) {
  __shared__ __align__(16) ushort Mb[64 * 256];   // 32 KB  M[px][k] fp16
  __shared__ __align__(16) ushort Xb[64 * 256];   // 32 KB  X^T[ch][k] fp16
  const int tid = threadIdx.x;
  const int lane = tid & 63, w = tid >> 6;
  const int l15 = lane & 15, lg = lane >> 4;
  const int l31 = lane & 31, lh = lane >> 5;

  // one-time zero of M (scatter slot-set is tile-invariant -> zeros persist)
  {
    const short8 z8 = {0,0,0,0,0,0,0,0};
    #pragma unroll
    for (int i = 0; i < 8; ++i)
      *reinterpret_cast<short8*>(&Mb[(tid + i * 256) * 8]) = z8;
  }

  const int b = blockIdx.x;
  const int tbase = (b & 7) * 1152 + (b >> 3) * 18;   // XCD-chunked tile bands
  const int p  = w * 16 + l15;             // scatter pixel
  const int pr = p >> 3, pc = p & 7;
  const int cb = lg << 4;                  // 16 channels of pixel p
  const int pb = w >> 1, cb2 = w & 1;      // GEMM: wave -> (px 32-block, ch 32-block)

  // pipeline registers
  float4 cv[4];                            // center channel quads
  float Rv[4][8];                          // new right-half halo cols
  float Lv[4][8];                          // left-half cols (fresh only)
  short8 rs[4];                            // packed right halves carried across tiles

  auto issue_loads = [&](int ti, int tj, bool fresh) {
    {
      const float* cp = x + ((size_t)((ti + pr) * WW + (tj + pc)) << 6) + cb;
      #pragma unroll
      for (int qd = 0; qd < 4; ++qd)
        cv[qd] = *reinterpret_cast<const float4*>(cp + qd * 4);
    }
    #pragma unroll
    for (int i = 0; i < 4; ++i) {
      const int r = w + 4 * i;
      if (r < 15) {
        const int gr = min(max(ti + r - 3, 0), HH - 1);
        const float* rowp = x + ((size_t)gr * WW << 6) + lane;
        #pragma unroll
        for (int s = 0; s < 8; ++s) {
          const int gc = min(max(tj + 5 + s, 0), WW - 1);
          Rv[i][s] = rowp[(size_t)gc << 6];
        }
        if (fresh) {
          #pragma unroll
          for (int s = 0; s < 8; ++s) {
            const int gc = min(max(tj - 3 + s, 0), WW - 1);
            Lv[i][s] = rowp[(size_t)gc << 6];
          }
        }
      }
    }
  };

  auto write_lds = [&](int ti, int tj, bool fresh) {
    // M scatter: sigmoid(center) fp16
    #pragma unroll
    for (int qd = 0; qd < 4; ++qd) {
      const float vs[4] = {cv[qd].x, cv[qd].y, cv[qd].z, cv[qd].w};
      #pragma unroll
      for (int j = 0; j < 4; ++j) {
        const int ch = cb + qd * 4 + j;
        const int k = ((pr + (ch >> 3)) << 4) | (pc + (ch & 7));
        Mb[eoff(p, k)] = f2h(sigmoidf(vs[j]));
      }
    }
    // X^T rows: left8 = reused old right (or fresh pack), right8 = new
    #pragma unroll
    for (int i = 0; i < 4; ++i) {
      const int r = w + 4 * i;
      if (r < 15) {
        const int gr = ti + r - 3;
        const bool rok = (unsigned)gr < (unsigned)HH;
        short8 left8;
        if (fresh) {
          #pragma unroll
          for (int s = 0; s < 8; ++s) {
            const int j = tj - 3 + s;
            const bool ok = rok && ((unsigned)j < (unsigned)WW);
            left8[s] = (short)f2h(ok ? Lv[i][s] : 0.f);
          }
        } else {
          left8 = rs[i];
        }
        short8 right8;
        #pragma unroll
        for (int s = 0; s < 8; ++s) {
          const int j = tj + 5 + s;
          const bool ok = rok && ((unsigned)j < (unsigned)WW);
          right8[s] = (short)f2h(ok ? Rv[i][s] : 0.f);
        }
        *reinterpret_cast<short8*>(&Xb[goff(lane, 2 * r)])     = left8;
        *reinterpret_cast<short8*>(&Xb[goff(lane, 2 * r + 1)]) = right8;
        rs[i] = right8;
      }
    }
  };

  f32x16 acc0, acc1;
  int pti = 0, ptj = 0;

  auto store_acc = [&](int ti, int tj) {
    #pragma unroll
    for (int reg = 0; reg < 16; ++reg) {
      const float v = acc0[reg] + acc1[reg];
      const int prow = (reg & 3) + 8 * (reg >> 2) + 4 * lh;
      const int p2 = pb * 32 + prow;
      const size_t gpx = (size_t)(ti + (p2 >> 3)) * WW + (tj + (p2 & 7));
      const int ch = cb2 * 32 + l31;
      if (F16OUT) ((ushort*)attout)[(gpx << 6) + ch] = f2h(v);
      else        ((float*)attout)[(gpx << 6) + ch] = v;
    }
  };

  // prologue: tile 0 (fresh) loads in flight
  issue_loads((tbase / 96) * 8, (tbase % 96) * 8, true);

  for (int t18 = 0; t18 < 18; ++t18) {
    const int tile = tbase + t18;
    const int ti = (tile / 96) * 8, tj = (tile % 96) * 8;
    const bool fresh = (t18 == 0) || (tj == 0);

    __syncthreads();                       // S0: prev tile's LDS reads done / init ordered
    write_lds(ti, tj, fresh);
    __syncthreads();                       // S1: M + X visible (no fresh VMEM -> cheap drain)

    if (t18 > 0) store_acc(pti, ptj);      // store previous tile (regs only)
    if (t18 < 17) {                        // prefetch next tile
      const int nt = tile + 1;
      issue_loads((nt / 96) * 8, (nt % 96) * 8, (nt % 96) == 0);
    }

    // GEMM: 15 k-steps of 32x32x16, two interleaved acc chains
    acc0 = (f32x16){0,0,0,0,0,0,0,0,0,0,0,0,0,0,0,0};
    acc1 = (f32x16){0,0,0,0,0,0,0,0,0,0,0,0,0,0,0,0};
    #pragma unroll
    for (int ks = 0; ks < 15; ++ks) {
      const int g = 2 * ks + lh;
      const half8 a  = *reinterpret_cast<const half8*>(&Mb[goff(pb * 32 + l31, g)]);
      const half8 bb = *reinterpret_cast<const half8*>(&Xb[goff(cb2 * 32 + l31, g)]);
      if (ks & 1) acc1 = __builtin_amdgcn_mfma_f32_32x32x16_f16(a, bb, acc1, 0, 0, 0);
      else        acc0 = __builtin_amdgcn_mfma_f32_32x32x16_f16(a, bb, acc0, 0, 0, 0);
    }
    pti = ti; ptj = tj;
  }
  store_acc(pti, ptj);                     // epilogue: last tile
}

// ---------------- K2: MLP + LN + head (persistent, 512 threads, fp16) ----------------
template<bool F16IN>
__global__ __launch_bounds__(512, 4)
void mlp_k2(const void* attv, const float* __restrict__ Ws,
            const float* __restrict__ bs, const float* __restrict__ lns,
            const float* __restrict__ lnb, const float* __restrict__ w_out,
            const float* __restrict__ b_out, float* x0_out,
            float* __restrict__ out1) {
  __shared__ __align__(16) ushort wt[4 * 64 * 64];   // 32 KB [layer][co][ci swz] fp16
  __shared__ __align__(16) ushort act[8 * 1152];     // 18 KB wave-private act fp16
  const int tid = threadIdx.x;
  const int lane = tid & 63, wid = tid >> 6;
  const int l15 = lane & 15, lg = lane >> 4;

  {
    const int row = tid >> 1;              // (layer<<6)|co
    const int l = row >> 6, co = row & 63;
    const int ci0 = (tid & 1) << 5;
    const int base = row << 6;
    for (int q = 0; q < 32; ++q) {
      const int ci = ci0 + q;
      const float v = Ws[(((l << 6) + ci) << 6) + co];
      const int e = ((((ci >> 3) ^ co) & 7) << 3) | (ci & 7);
      wt[base + e] = f2h(v);
    }
  }
  float bias[4][4], sc[4][4], lbv[4][4];
  #pragma unroll
  for (int L = 0; L < 4; ++L)
    #pragma unroll
    for (int nb = 0; nb < 4; ++nb) {
      const int ch = (L << 6) + nb * 16 + l15;
      bias[L][nb] = bs[ch]; sc[L][nb] = lns[ch]; lbv[L][nb] = lnb[ch];
    }
  float wo[4];
  #pragma unroll
  for (int nb = 0; nb < 4; ++nb) wo[nb] = w_out[nb * 16 + l15];
  const float b0s = b_out[0];
  __syncthreads();

  ushort* const acth = act + wid * 1152;   // [16][72]

  for (int it = 0; it < 18; ++it) {
    const int chunk = blockIdx.x + (it << 8);
    const int px_base = chunk * 128 + wid * 16;

    half8 a0, a1;
    if (F16IN) {
      const ushort* ap = (const ushort*)attv + ((size_t)(px_base + l15) << 6) + lg * 8;
      a0 = *reinterpret_cast<const half8*>(ap);
      a1 = *reinterpret_cast<const half8*>(ap + 32);
    } else {
      const float* ap = (const float*)attv + ((size_t)(px_base + l15) << 6) + lg * 8;
      const float4 f0 = *reinterpret_cast<const float4*>(ap);
      const float4 f1 = *reinterpret_cast<const float4*>(ap + 4);
      const float4 f2 = *reinterpret_cast<const float4*>(ap + 32);
      const float4 f3 = *reinterpret_cast<const float4*>(ap + 36);
      a0[0]=(_Float16)f0.x; a0[1]=(_Float16)f0.y; a0[2]=(_Float16)f0.z; a0[3]=(_Float16)f0.w;
      a0[4]=(_Float16)f1.x; a0[5]=(_Float16)f1.y; a0[6]=(_Float16)f1.z; a0[7]=(_Float16)f1.w;
      a1[0]=(_Float16)f2.x; a1[1]=(_Float16)f2.y; a1[2]=(_Float16)f2.z; a1[3]=(_Float16)f2.w;
      a1[4]=(_Float16)f3.x; a1[5]=(_Float16)f3.y; a1[6]=(_Float16)f3.z; a1[7]=(_Float16)f3.w;
    }

    float y[4][4];
    #pragma unroll
    for (int layer = 0; layer < 4; ++layer) {
      if (layer > 0) {
        a0 = *reinterpret_cast<const half8*>(&acth[l15 * 72 + lg * 8]);
        a1 = *reinterpret_cast<const half8*>(&acth[l15 * 72 + 32 + lg * 8]);
      }
      f32x4 z[4];
      #pragma unroll
      for (int nb = 0; nb < 4; ++nb) {
        const int co = nb * 16 + l15;
        const int wb = ((layer << 6) + co) << 6;
        const int e0 = (((lg    ) ^ co) & 7) << 3;
        const int e1 = (((lg + 4) ^ co) & 7) << 3;
        const half8 b0 = *reinterpret_cast<const half8*>(&wt[wb + e0]);
        const half8 b1 = *reinterpret_cast<const half8*>(&wt[wb + e1]);
        z[nb] = {0.f, 0.f, 0.f, 0.f};
        z[nb] = __builtin_amdgcn_mfma_f32_16x16x32_f16(a0, b0, z[nb], 0, 0, 0);
        z[nb] = __builtin_amdgcn_mfma_f32_16x16x32_f16(a1, b1, z[nb], 0, 0, 0);
      }
      #pragma unroll
      for (int reg = 0; reg < 4; ++reg) {
        float s = 0.f, ss = 0.f;
        #pragma unroll
        for (int nb = 0; nb < 4; ++nb) {
          float v = z[nb][reg] + bias[layer][nb];
          v = fmaxf(v, 0.f);
          y[reg][nb] = v;
          s += v; ss += v * v;
        }
        #pragma unroll
        for (int m = 1; m <= 8; m <<= 1) { s += __shfl_xor(s, m, 64); ss += __shfl_xor(ss, m, 64); }
        const float mu = s * 0.015625f;
        const float var = ss * 0.015625f - mu * mu;
        const float rstd = rsqrtf(var + 1e-6f);
        #pragma unroll
        for (int nb = 0; nb < 4; ++nb)
          y[reg][nb] = (y[reg][nb] - mu) * rstd * sc[layer][nb] + lbv[layer][nb];
      }
      if (layer < 3) {
        #pragma unroll
        for (int reg = 0; reg < 4; ++reg) {
          const int row = lg * 4 + reg;
          #pragma unroll
          for (int nb = 0; nb < 4; ++nb)
            acth[row * 72 + nb * 16 + l15] = f2h(y[reg][nb]);
        }
      }
    }

    #pragma unroll
    for (int reg = 0; reg < 4; ++reg) {
      const size_t pxg = (size_t)px_base + lg * 4 + reg;
      #pragma unroll
      for (int nb = 0; nb < 4; ++nb)
        x0_out[(pxg << 6) + nb * 16 + l15] = y[reg][nb];
      float part = y[reg][0] * wo[0] + y[reg][1] * wo[1] + y[reg][2] * wo[2] + y[reg][3] * wo[3];
      #pragma unroll
      for (int m = 1; m <= 8; m <<= 1) part += __shfl_xor(part, m, 64);
      if (l15 == 0) out1[pxg] = part + b0s;
    }
  }
}

extern "C" void kernel_launch(void* const* d_in, const int* in_sizes, int n_in,
                              void* d_out, int out_size, void* d_ws, size_t ws_size,
                              hipStream_t stream) {
  const float* x     = (const float*)d_in[0];
  const float* Ws    = (const float*)d_in[1];
  const float* bs    = (const float*)d_in[2];
  const float* lns   = (const float*)d_in[3];
  const float* lnbv  = (const float*)d_in[4];
  const float* w_out = (const float*)d_in[5];
  const float* b_out = (const float*)d_in[6];
  float* x0_out = (float*)d_out;
  float* out1   = x0_out + (size_t)HWPX * 64;

  if (ws_size >= (size_t)HWPX * 64 * sizeof(ushort)) {
    // fp16 att in workspace
    ushort* atth = (ushort*)d_ws;
    att_k1<true><<<512, 256, 0, stream>>>(x, atth);
    mlp_k2<true><<<256, 512, 0, stream>>>(atth, Ws, bs, lns, lnbv,
                                          w_out, b_out, x0_out, out1);
  } else {
    // f32 att in-place over the x0 region (block-private read-before-write in K2)
    att_k1<false><<<512, 256, 0, stream>>>(x, d_out);
    mlp_k2<false><<<256, 512, 0, stream>>>(d_out, Ws, bs, lns, lnbv,
                                           w_out, b_out, x0_out, out1);
  }
}

// Round 11
// 187.666 us; speedup vs baseline: 2.9637x; 1.0430x over previous
//
#include <hip/hip_runtime.h>
#include <hip/hip_bf16.h>

// CellAnnotator R11 = R10 with the wt-staging bug fixed (uint4 = 8 ushorts; R10 strode
// 16 ushorts with q<5, leaving half of every folded-weight row uninitialized).
//  K1 (R9, proven): per 8x8 tile out = M@X via 32x32x16 fp16 MFMA, phase-rotated pipeline.
//  K2: swapped-operand 32x32x16 MFMA (A=W', B=act) -> lane owns 32ch of 1 px; LN reduce =
//      in-lane + one shfl_xor(32). Affine folded into W' (K0): k-row 64=bias', 65=colsum;
//      act rows carry rstd*v and -(mu*rstd); K=80. Layer-3 params hoisted to regs.

#define HH 768
#define WW 768
#define HWPX (HH*WW)

typedef __attribute__((ext_vector_type(8))) short short8;
typedef __attribute__((ext_vector_type(8))) _Float16 half8;
typedef __attribute__((ext_vector_type(4))) float f32x4;
typedef __attribute__((ext_vector_type(16))) float f32x16;

union hcvt { _Float16 h; ushort u; };
__device__ __forceinline__ ushort f2h(float f) { hcvt c; c.h = (_Float16)f; return c.u; }
__device__ __forceinline__ float sigmoidf(float v) { return 1.f / (1.f + __expf(-v)); }

// K1 LDS: row pitch 256 ushorts, XOR-swizzle low-3 bits of 8-elem group by row&7.
__device__ __forceinline__ int goff(int row, int g) {
  return (row << 8) + (((g & ~7) | ((g ^ row) & 7)) << 3);
}
__device__ __forceinline__ int eoff(int row, int k) {
  const int g = k >> 3;
  return (row << 8) + (((g & ~7) | ((g ^ row) & 7)) << 3) + (k & 7);
}

// ---------------- K0: fold params into weights ----------------
// Wfg[(L*64+co)*80 + ci] = fp16( (L>0 ? lns[L-1][ci] : 1) * Ws[L][ci][co] )   ci<64
//                  [64] = fp16( bs[L][co] + (L>0 ? sum_ci lnb[L-1][ci]*Ws[L][ci][co] : 0) )
//                  [65] = fp16( colsum of scaled W )          [66..79] = 0
__global__ __launch_bounds__(256)
void prep_wf(const float* __restrict__ Ws, const float* __restrict__ bs,
             const float* __restrict__ lns, const float* __restrict__ lnb,
             ushort* __restrict__ Wfg) {
  const int L = threadIdx.x >> 6, co = threadIdx.x & 63;
  float bias = bs[L * 64 + co];
  float colsum = 0.f;
  ushort* row = Wfg + (size_t)(L * 64 + co) * 80;
  for (int ci = 0; ci < 64; ++ci) {
    const float w = Ws[((L * 64 + ci) << 6) + co];
    const float sc = (L > 0) ? lns[(L - 1) * 64 + ci] : 1.f;
    const float wp = sc * w;
    if (L > 0) bias += lnb[(L - 1) * 64 + ci] * w;
    colsum += wp;
    row[ci] = f2h(wp);
  }
  row[64] = f2h(bias);
  row[65] = f2h(colsum);
  for (int q = 66; q < 80; ++q) row[q] = 0;
}

// ---------------- K1: att (unchanged from R9) ----------------
template<bool F16OUT>
__global__ __launch_bounds__(256, 2)
void att_k1(const float* __restrict__ x, void* __restrict__ attout) {
  __shared__ __align__(16) ushort Mb[64 * 256];
  __shared__ __align__(16) ushort Xb[64 * 256];
  const int tid = threadIdx.x;
  const int lane = tid & 63, w = tid >> 6;
  const int l15 = lane & 15, lg = lane >> 4;
  const int l31 = lane & 31, lh = lane >> 5;

  {
    const short8 z8 = {0,0,0,0,0,0,0,0};
    #pragma unroll
    for (int i = 0; i < 8; ++i)
      *reinterpret_cast<short8*>(&Mb[(tid + i * 256) * 8]) = z8;
  }

  const int b = blockIdx.x;
  const int tbase = (b & 7) * 1152 + (b >> 3) * 18;
  const int p  = w * 16 + l15;
  const int pr = p >> 3, pc = p & 7;
  const int cb = lg << 4;
  const int pb = w >> 1, cb2 = w & 1;

  float4 cv[4];
  float Rv[4][8];
  float Lv[4][8];
  short8 rs[4];

  auto issue_loads = [&](int ti, int tj, bool fresh) {
    {
      const float* cp = x + ((size_t)((ti + pr) * WW + (tj + pc)) << 6) + cb;
      #pragma unroll
      for (int qd = 0; qd < 4; ++qd)
        cv[qd] = *reinterpret_cast<const float4*>(cp + qd * 4);
    }
    #pragma unroll
    for (int i = 0; i < 4; ++i) {
      const int r = w + 4 * i;
      if (r < 15) {
        const int gr = min(max(ti + r - 3, 0), HH - 1);
        const float* rowp = x + ((size_t)gr * WW << 6) + lane;
        #pragma unroll
        for (int s = 0; s < 8; ++s) {
          const int gc = min(max(tj + 5 + s, 0), WW - 1);
          Rv[i][s] = rowp[(size_t)gc << 6];
        }
        if (fresh) {
          #pragma unroll
          for (int s = 0; s < 8; ++s) {
            const int gc = min(max(tj - 3 + s, 0), WW - 1);
            Lv[i][s] = rowp[(size_t)gc << 6];
          }
        }
      }
    }
  };

  auto write_lds = [&](int ti, int tj, bool fresh) {
    #pragma unroll
    for (int qd = 0; qd < 4; ++qd) {
      const float vs[4] = {cv[qd].x, cv[qd].y, cv[qd].z, cv[qd].w};
      #pragma unroll
      for (int j = 0; j < 4; ++j) {
        const int ch = cb + qd * 4 + j;
        const int k = ((pr + (ch >> 3)) << 4) | (pc + (ch & 7));
        Mb[eoff(p, k)] = f2h(sigmoidf(vs[j]));
      }
    }
    #pragma unroll
    for (int i = 0; i < 4; ++i) {
      const int r = w + 4 * i;
      if (r < 15) {
        const int gr = ti + r - 3;
        const bool rok = (unsigned)gr < (unsigned)HH;
        short8 left8;
        if (fresh) {
          #pragma unroll
          for (int s = 0; s < 8; ++s) {
            const int j = tj - 3 + s;
            const bool ok = rok && ((unsigned)j < (unsigned)WW);
            left8[s] = (short)f2h(ok ? Lv[i][s] : 0.f);
          }
        } else {
          left8 = rs[i];
        }
        short8 right8;
        #pragma unroll
        for (int s = 0; s < 8; ++s) {
          const int j = tj + 5 + s;
          const bool ok = rok && ((unsigned)j < (unsigned)WW);
          right8[s] = (short)f2h(ok ? Rv[i][s] : 0.f);
        }
        *reinterpret_cast<short8*>(&Xb[goff(lane, 2 * r)])     = left8;
        *reinterpret_cast<short8*>(&Xb[goff(lane, 2 * r + 1)]) = right8;
        rs[i] = right8;
      }
    }
  };

  f32x16 acc0, acc1;
  int pti = 0, ptj = 0;

  auto store_acc = [&](int ti, int tj) {
    #pragma unroll
    for (int reg = 0; reg < 16; ++reg) {
      const float v = acc0[reg] + acc1[reg];
      const int prow = (reg & 3) + 8 * (reg >> 2) + 4 * lh;
      const int p2 = pb * 32 + prow;
      const size_t gpx = (size_t)(ti + (p2 >> 3)) * WW + (tj + (p2 & 7));
      const int ch = cb2 * 32 + l31;
      if (F16OUT) ((ushort*)attout)[(gpx << 6) + ch] = f2h(v);
      else        ((float*)attout)[(gpx << 6) + ch] = v;
    }
  };

  issue_loads((tbase / 96) * 8, (tbase % 96) * 8, true);

  for (int t18 = 0; t18 < 18; ++t18) {
    const int tile = tbase + t18;
    const int ti = (tile / 96) * 8, tj = (tile % 96) * 8;
    const bool fresh = (t18 == 0) || (tj == 0);

    __syncthreads();
    write_lds(ti, tj, fresh);
    __syncthreads();

    if (t18 > 0) store_acc(pti, ptj);
    if (t18 < 17) {
      const int nt = tile + 1;
      issue_loads((nt / 96) * 8, (nt % 96) * 8, (nt % 96) == 0);
    }

    acc0 = (f32x16){0,0,0,0,0,0,0,0,0,0,0,0,0,0,0,0};
    acc1 = (f32x16){0,0,0,0,0,0,0,0,0,0,0,0,0,0,0,0};
    #pragma unroll
    for (int ks = 0; ks < 15; ++ks) {
      const int g = 2 * ks + lh;
      const half8 a  = *reinterpret_cast<const half8*>(&Mb[goff(pb * 32 + l31, g)]);
      const half8 bb = *reinterpret_cast<const half8*>(&Xb[goff(cb2 * 32 + l31, g)]);
      if (ks & 1) acc1 = __builtin_amdgcn_mfma_f32_32x32x16_f16(a, bb, acc1, 0, 0, 0);
      else        acc0 = __builtin_amdgcn_mfma_f32_32x32x16_f16(a, bb, acc0, 0, 0, 0);
    }
    pti = ti; ptj = tj;
  }
  store_acc(pti, ptj);
}

// ---------------- K2: MLP + LN + head (swapped 32x32, folded params) ----------------
__device__ __forceinline__ float zsel(const f32x16& z0, const f32x16& z1, int nb, int idx) {
  return nb ? z1[idx] : z0[idx];
}

template<bool F16IN>
__global__ __launch_bounds__(512, 2)
void mlp_k2(const void* attv, const ushort* __restrict__ Wfg,
            const float* __restrict__ lns, const float* __restrict__ lnb,
            const float* __restrict__ w_out, const float* __restrict__ b_out,
            float* x0_out, float* __restrict__ out1) {
  __shared__ __align__(16) ushort wt[4 * 64 * 88];   // 45 KB [L*64+co][ci] pitch 88
  __shared__ __align__(16) ushort act[8][32 * 88];   // 45 KB wave-private [px][ci] pitch 88
  __shared__ __align__(16) ushort kpat[16];          // layer-0 kstep-4 pattern {1,0,...}
  const int tid = threadIdx.x;
  const int lane = tid & 63, wid = tid >> 6;
  const int l31 = lane & 31, lh = lane >> 5;

  // stage folded weights: 10 x uint4 (= 8 ushorts each) per 80-ushort row.
  // R10 BUG was q<5 with stride 16 ushorts -> half of each row uninitialized.
  for (int idx = tid; idx < 4 * 64 * 10; idx += 512) {
    const int row = idx / 10, q = idx - row * 10;
    *reinterpret_cast<uint4*>(&wt[row * 88 + q * 8]) =
        *reinterpret_cast<const uint4*>(&Wfg[(size_t)row * 80 + q * 8]);
  }
  // act const tail per px row: [64]=1 (bias row), [65..87]=0 ([65] rewritten per layer)
  for (int idx = tid; idx < 256; idx += 512) {
    ushort* rp = &act[idx >> 5][(idx & 31) * 88];
    for (int q = 64; q < 88; ++q) rp[q] = 0;
    rp[64] = 0x3C00;
  }
  if (tid < 16) kpat[tid] = (tid == 0) ? (ushort)0x3C00 : (ushort)0;

  // hoist layer-3 LN params + head weights (per-lane ch set is iter-invariant)
  float sc3[2][4][4], lb3[2][4][4], wo3[2][4][4];
  #pragma unroll
  for (int nb = 0; nb < 2; ++nb)
    #pragma unroll
    for (int hi = 0; hi < 4; ++hi)
      #pragma unroll
      for (int j = 0; j < 4; ++j) {
        const int ch = nb * 32 + hi * 8 + lh * 4 + j;
        sc3[nb][hi][j] = lns[192 + ch];
        lb3[nb][hi][j] = lnb[192 + ch];
        wo3[nb][hi][j] = w_out[ch];
      }
  const float b0s = b_out[0];
  __syncthreads();

  ushort* const myact = act[wid];

  for (int it = 0; it < 9; ++it) {
    const int px = ((it * 256 + (int)blockIdx.x) * 8 + wid) * 32 + l31;

    half8 bfr[5];
    if (F16IN) {
      const ushort* ap = (const ushort*)attv + ((size_t)px << 6) + lh * 8;
      #pragma unroll
      for (int g = 0; g < 4; ++g)
        bfr[g] = *reinterpret_cast<const half8*>(ap + g * 16);
    } else {
      const float* ap = (const float*)attv + ((size_t)px << 6) + lh * 8;
      #pragma unroll
      for (int g = 0; g < 4; ++g) {
        const float4 fa = *reinterpret_cast<const float4*>(ap + g * 16);
        const float4 fb = *reinterpret_cast<const float4*>(ap + g * 16 + 4);
        half8 h;
        h[0]=(_Float16)fa.x; h[1]=(_Float16)fa.y; h[2]=(_Float16)fa.z; h[3]=(_Float16)fa.w;
        h[4]=(_Float16)fb.x; h[5]=(_Float16)fb.y; h[6]=(_Float16)fb.z; h[7]=(_Float16)fb.w;
        bfr[g] = h;
      }
    }
    bfr[4] = *reinterpret_cast<const half8*>(&kpat[lh * 8]);

    f32x16 z0, z1;
    float mu = 0.f, rstd = 1.f;
    #pragma unroll
    for (int L = 0; L < 4; ++L) {
      if (L > 0) {
        #pragma unroll
        for (int g = 0; g < 5; ++g)
          bfr[g] = *reinterpret_cast<const half8*>(&myact[l31 * 88 + g * 16 + lh * 8]);
      }
      z0 = (f32x16){0,0,0,0,0,0,0,0,0,0,0,0,0,0,0,0};
      z1 = (f32x16){0,0,0,0,0,0,0,0,0,0,0,0,0,0,0,0};
      #pragma unroll
      for (int g = 0; g < 5; ++g) {
        const half8 a0 = *reinterpret_cast<const half8*>(&wt[(L * 64      + l31) * 88 + g * 16 + lh * 8]);
        const half8 a1 = *reinterpret_cast<const half8*>(&wt[(L * 64 + 32 + l31) * 88 + g * 16 + lh * 8]);
        z0 = __builtin_amdgcn_mfma_f32_32x32x16_f16(a0, bfr[g], z0, 0, 0, 0);
        z1 = __builtin_amdgcn_mfma_f32_32x32x16_f16(a1, bfr[g], z1, 0, 0, 0);
      }
      // relu + sums (4 partial accumulators to break the chain)
      float sp[4] = {0.f, 0.f, 0.f, 0.f}, qp[4] = {0.f, 0.f, 0.f, 0.f};
      #pragma unroll
      for (int r = 0; r < 16; ++r) {
        const float v0 = fmaxf(z0[r], 0.f); z0[r] = v0;
        const float v1 = fmaxf(z1[r], 0.f); z1[r] = v1;
        sp[r & 3] += v0 + v1;
        qp[r & 3] += v0 * v0 + v1 * v1;
      }
      float s = (sp[0] + sp[1]) + (sp[2] + sp[3]);
      float qq = (qp[0] + qp[1]) + (qp[2] + qp[3]);
      s  += __shfl_xor(s, 32, 64);
      qq += __shfl_xor(qq, 32, 64);
      mu = s * 0.015625f;
      const float var = qq * 0.015625f - mu * mu;
      rstd = rsqrtf(var + 1e-6f);
      if (L < 3) {
        // act := rstd*v (ci<64); row 65 := -(mu*rstd)  [row 64 stays 1]
        #pragma unroll
        for (int nb = 0; nb < 2; ++nb)
          #pragma unroll
          for (int hi = 0; hi < 4; ++hi) {
            ushort4 pk;
            pk.x = f2h(rstd * zsel(z0, z1, nb, hi * 4 + 0));
            pk.y = f2h(rstd * zsel(z0, z1, nb, hi * 4 + 1));
            pk.z = f2h(rstd * zsel(z0, z1, nb, hi * 4 + 2));
            pk.w = f2h(rstd * zsel(z0, z1, nb, hi * 4 + 3));
            *reinterpret_cast<ushort4*>(&myact[l31 * 88 + nb * 32 + hi * 8 + lh * 4]) = pk;
          }
        if (lh == 0) myact[l31 * 88 + 65] = f2h(-(mu * rstd));
      }
    }

    // layer-3 epilogue: y = v*(rstd*sc3) + (lb3 - mu*rstd*sc3); x0 + head
    const float t = mu * rstd;
    float part0 = 0.f, part1 = 0.f;
    #pragma unroll
    for (int nb = 0; nb < 2; ++nb)
      #pragma unroll
      for (int hi = 0; hi < 4; ++hi) {
        f32x4 yv;
        #pragma unroll
        for (int j = 0; j < 4; ++j) {
          const float v = zsel(z0, z1, nb, hi * 4 + j);
          const float y = v * (rstd * sc3[nb][hi][j]) + (lb3[nb][hi][j] - t * sc3[nb][hi][j]);
          yv[j] = y;
          if (j & 1) part1 += y * wo3[nb][hi][j];
          else       part0 += y * wo3[nb][hi][j];
        }
        *reinterpret_cast<f32x4*>(&x0_out[((size_t)px << 6) + nb * 32 + hi * 8 + lh * 4]) = yv;
      }
    float part = part0 + part1;
    part += __shfl_xor(part, 32, 64);
    if (lh == 0) out1[px] = part + b0s;
  }
}

extern "C" void kernel_launch(void* const* d_in, const int* in_sizes, int n_in,
                              void* d_out, int out_size, void* d_ws, size_t ws_size,
                              hipStream_t stream) {
  const float* x     = (const float*)d_in[0];
  const float* Ws    = (const float*)d_in[1];
  const float* bs    = (const float*)d_in[2];
  const float* lns   = (const float*)d_in[3];
  const float* lnbv  = (const float*)d_in[4];
  const float* w_out = (const float*)d_in[5];
  const float* b_out = (const float*)d_in[6];
  float* x0_out = (float*)d_out;
  float* out1   = x0_out + (size_t)HWPX * 64;

  const size_t attBytes = (size_t)HWPX * 64 * sizeof(ushort);   // 75.5 MB
  if (ws_size >= attBytes + 65536) {
    ushort* atth = (ushort*)d_ws;
    ushort* Wfg  = (ushort*)((char*)d_ws + attBytes);
    prep_wf<<<1, 256, 0, stream>>>(Ws, bs, lns, lnbv, Wfg);
    att_k1<true><<<512, 256, 0, stream>>>(x, atth);
    mlp_k2<true><<<256, 512, 0, stream>>>(atth, Wfg, lns, lnbv,
                                          w_out, b_out, x0_out, out1);
  } else {
    // f32 att in-place over x0 region (each px chunk read-then-written by one block)
    ushort* Wfg = (ushort*)d_ws;                                 // needs 41 KB
    prep_wf<<<1, 256, 0, stream>>>(Ws, bs, lns, lnbv, Wfg);
    att_k1<false><<<512, 256, 0, stream>>>(x, d_out);
    mlp_k2<false><<<256, 512, 0, stream>>>(d_out, Wfg, lns, lnbv,
                                           w_out, b_out, x0_out, out1);
  }
}

// Round 13
// 179.621 us; speedup vs baseline: 3.0964x; 1.0448x over previous
//
#include <hip/hip_runtime.h>
#include <hip/hip_bf16.h>

// CellAnnotator R13 = R12 with the scr LDS size bug fixed: partial-accumulator scratch is
// [tile][reg-quad][lane] x float4 = 4096 floats (16 KB); R12 declared 1024 floats (4 KB)
// and wrote 12 KB out of bounds. LDS = 32+32+16 = 80 KB -> 2 blocks/CU, 16 waves/CU.
//  K1: 512 threads, 8 waves; each 32x32 output tile computed by a wave PAIR splitting
//      K=240 (ks 0-6 / 7-14); kh=1 partials cross via scr (write post-GEMM, read post-S0).
//  K2/prep: unchanged (R11, proven).

#define HH 768
#define WW 768
#define HWPX (HH*WW)

typedef __attribute__((ext_vector_type(8))) short short8;
typedef __attribute__((ext_vector_type(8))) _Float16 half8;
typedef __attribute__((ext_vector_type(4))) float f32x4;
typedef __attribute__((ext_vector_type(16))) float f32x16;

union hcvt { _Float16 h; ushort u; };
__device__ __forceinline__ ushort f2h(float f) { hcvt c; c.h = (_Float16)f; return c.u; }
__device__ __forceinline__ float sigmoidf(float v) { return 1.f / (1.f + __expf(-v)); }

// K1 LDS: row pitch 256 ushorts, XOR-swizzle low-3 bits of 8-elem group by row&7.
__device__ __forceinline__ int goff(int row, int g) {
  return (row << 8) + (((g & ~7) | ((g ^ row) & 7)) << 3);
}
__device__ __forceinline__ int eoff(int row, int k) {
  const int g = k >> 3;
  return (row << 8) + (((g & ~7) | ((g ^ row) & 7)) << 3) + (k & 7);
}

// ---------------- K0: fold params into weights (unchanged) ----------------
__global__ __launch_bounds__(256)
void prep_wf(const float* __restrict__ Ws, const float* __restrict__ bs,
             const float* __restrict__ lns, const float* __restrict__ lnb,
             ushort* __restrict__ Wfg) {
  const int L = threadIdx.x >> 6, co = threadIdx.x & 63;
  float bias = bs[L * 64 + co];
  float colsum = 0.f;
  ushort* row = Wfg + (size_t)(L * 64 + co) * 80;
  for (int ci = 0; ci < 64; ++ci) {
    const float w = Ws[((L * 64 + ci) << 6) + co];
    const float sc = (L > 0) ? lns[(L - 1) * 64 + ci] : 1.f;
    const float wp = sc * w;
    if (L > 0) bias += lnb[(L - 1) * 64 + ci] * w;
    colsum += wp;
    row[ci] = f2h(wp);
  }
  row[64] = f2h(bias);
  row[65] = f2h(colsum);
  for (int q = 66; q < 80; ++q) row[q] = 0;
}

// ---------------- K1: att (512 threads, k-split wave pairs) ----------------
template<bool F16OUT>
__global__ __launch_bounds__(512, 4)
void att_k1(const float* __restrict__ x, void* __restrict__ attout) {
  __shared__ __align__(16) ushort Mb[64 * 256];        // 32 KB  M[px][k] fp16
  __shared__ __align__(16) ushort Xb[64 * 256];        // 32 KB  X^T[ch][k] fp16
  __shared__ __align__(16) float  scr[4 * 4 * 64 * 4]; // 16 KB  [tile][reg4][lane]x4 partials
  const int tid = threadIdx.x;
  const int lane = tid & 63, w = tid >> 6;             // 8 waves
  const int l15 = lane & 15, lg = lane >> 4;
  const int l31 = lane & 31, lh = lane >> 5;
  const int ot = w & 3;                                // output tile 0..3
  const int pb = ot >> 1, cb2 = ot & 1;                // (px 32-block, ch 32-block)
  const int kh = w >> 2;                               // k-half 0/1

  // one-time zero of M (scatter slot-set is tile-invariant -> zeros persist)
  {
    const short8 z8 = {0,0,0,0,0,0,0,0};
    #pragma unroll
    for (int i = 0; i < 4; ++i)
      *reinterpret_cast<short8*>(&Mb[(tid + i * 512) * 8]) = z8;
  }

  const int b = blockIdx.x;
  const int tbase = (b & 7) * 1152 + (b >> 3) * 18;    // XCD-chunked tile bands
  // M-scatter ownership: pixel p = (w&3)*16+l15, 8 channels from (kh,lg)
  const int p  = (w & 3) * 16 + l15;
  const int pr = p >> 3, pc = p & 7;
  const int cb = ((kh << 2) + lg) << 3;                // channel base 0,8,...,56
  const int kr0 = pr + (cb >> 3);                      // M k-row for this thread's 8 ch

  // pipeline registers (2 halo rows per thread: r = w, w+8)
  float4 cv[2];
  float Rv[2][8];
  float Lv[2][8];
  short8 rs[2];

  auto issue_loads = [&](int ti, int tj, bool fresh) {
    {
      const float* cp = x + ((size_t)((ti + pr) * WW + (tj + pc)) << 6) + cb;
      cv[0] = *reinterpret_cast<const float4*>(cp);
      cv[1] = *reinterpret_cast<const float4*>(cp + 4);
    }
    #pragma unroll
    for (int i = 0; i < 2; ++i) {
      const int r = w + 8 * i;
      if (r < 15) {
        const int gr = min(max(ti + r - 3, 0), HH - 1);
        const float* rowp = x + ((size_t)gr * WW << 6) + lane;
        #pragma unroll
        for (int s = 0; s < 8; ++s) {
          const int gc = min(max(tj + 5 + s, 0), WW - 1);
          Rv[i][s] = rowp[(size_t)gc << 6];
        }
        if (fresh) {
          #pragma unroll
          for (int s = 0; s < 8; ++s) {
            const int gc = min(max(tj - 3 + s, 0), WW - 1);
            Lv[i][s] = rowp[(size_t)gc << 6];
          }
        }
      }
    }
  };

  auto write_lds = [&](int ti, int tj, bool fresh) {
    // M scatter: sigmoid(center) fp16, 8 channels
    #pragma unroll
    for (int qd = 0; qd < 2; ++qd) {
      const float vs[4] = {cv[qd].x, cv[qd].y, cv[qd].z, cv[qd].w};
      #pragma unroll
      for (int j = 0; j < 4; ++j) {
        const int k = (kr0 << 4) + pc + qd * 4 + j;
        Mb[eoff(p, k)] = f2h(sigmoidf(vs[j]));
      }
    }
    // X^T rows: left8 = reused old right (or fresh pack), right8 = new
    #pragma unroll
    for (int i = 0; i < 2; ++i) {
      const int r = w + 8 * i;
      if (r < 15) {
        const int gr = ti + r - 3;
        const bool rok = (unsigned)gr < (unsigned)HH;
        short8 left8;
        if (fresh) {
          #pragma unroll
          for (int s = 0; s < 8; ++s) {
            const int j = tj - 3 + s;
            const bool ok = rok && ((unsigned)j < (unsigned)WW);
            left8[s] = (short)f2h(ok ? Lv[i][s] : 0.f);
          }
        } else {
          left8 = rs[i];
        }
        short8 right8;
        #pragma unroll
        for (int s = 0; s < 8; ++s) {
          const int j = tj + 5 + s;
          const bool ok = rok && ((unsigned)j < (unsigned)WW);
          right8[s] = (short)f2h(ok ? Rv[i][s] : 0.f);
        }
        *reinterpret_cast<short8*>(&Xb[goff(lane, 2 * r)])     = left8;
        *reinterpret_cast<short8*>(&Xb[goff(lane, 2 * r + 1)]) = right8;
        rs[i] = right8;
      }
    }
  };

  f32x16 acc;
  int pti = 0, ptj = 0;

  auto store_acc = [&](int ti, int tj) {   // kh==0 waves only
    #pragma unroll
    for (int reg = 0; reg < 16; ++reg) {
      const float v = acc[reg];
      const int prow = (reg & 3) + 8 * (reg >> 2) + 4 * lh;
      const int p2 = pb * 32 + prow;
      const size_t gpx = (size_t)(ti + (p2 >> 3)) * WW + (tj + (p2 & 7));
      const int ch = cb2 * 32 + l31;
      if (F16OUT) ((ushort*)attout)[(gpx << 6) + ch] = f2h(v);
      else        ((float*)attout)[(gpx << 6) + ch] = v;
    }
  };

  issue_loads((tbase / 96) * 8, (tbase % 96) * 8, true);

  for (int t18 = 0; t18 < 18; ++t18) {
    const int tile = tbase + t18;
    const int ti = (tile / 96) * 8, tj = (tile % 96) * 8;
    const bool fresh = (t18 == 0) || (tj == 0);

    __syncthreads();                       // S0: prev LDS reads done; kh=1 scr writes visible
    if (kh == 0 && t18 > 0) {              // fold tile t-1 kh=1 partials into acc
      #pragma unroll
      for (int q = 0; q < 4; ++q) {
        const float4 pv = *reinterpret_cast<const float4*>(&scr[ot * 1024 + q * 256 + lane * 4]);
        acc[q * 4 + 0] += pv.x; acc[q * 4 + 1] += pv.y;
        acc[q * 4 + 2] += pv.z; acc[q * 4 + 3] += pv.w;
      }
    }
    write_lds(ti, tj, fresh);
    __syncthreads();                       // S1: M + X visible
    if (kh == 0 && t18 > 0) store_acc(pti, ptj);
    if (t18 < 17) {
      const int nt = tile + 1;
      issue_loads((nt / 96) * 8, (nt % 96) * 8, (nt % 96) == 0);
    }

    // GEMM: this wave's k-half (kh=0: ks 0..6, kh=1: ks 7..14)
    acc = (f32x16){0,0,0,0,0,0,0,0,0,0,0,0,0,0,0,0};
    const int ks0 = kh ? 7 : 0, ks1 = kh ? 15 : 7;
    #pragma unroll 8
    for (int ks = ks0; ks < ks1; ++ks) {
      const int g = 2 * ks + lh;
      const half8 a  = *reinterpret_cast<const half8*>(&Mb[goff(pb * 32 + l31, g)]);
      const half8 bb = *reinterpret_cast<const half8*>(&Xb[goff(cb2 * 32 + l31, g)]);
      acc = __builtin_amdgcn_mfma_f32_32x32x16_f16(a, bb, acc, 0, 0, 0);
    }
    if (kh == 1) {                         // publish partial (read at next S0)
      #pragma unroll
      for (int q = 0; q < 4; ++q) {
        float4 pv;
        pv.x = acc[q * 4 + 0]; pv.y = acc[q * 4 + 1];
        pv.z = acc[q * 4 + 2]; pv.w = acc[q * 4 + 3];
        *reinterpret_cast<float4*>(&scr[ot * 1024 + q * 256 + lane * 4]) = pv;
      }
    }
    pti = ti; ptj = tj;
  }
  __syncthreads();                         // final: scr for tile 17 visible
  if (kh == 0) {
    #pragma unroll
    for (int q = 0; q < 4; ++q) {
      const float4 pv = *reinterpret_cast<const float4*>(&scr[ot * 1024 + q * 256 + lane * 4]);
      acc[q * 4 + 0] += pv.x; acc[q * 4 + 1] += pv.y;
      acc[q * 4 + 2] += pv.z; acc[q * 4 + 3] += pv.w;
    }
    store_acc(pti, ptj);
  }
}

// ---------------- K2: MLP + LN + head (unchanged from R11) ----------------
__device__ __forceinline__ float zsel(const f32x16& z0, const f32x16& z1, int nb, int idx) {
  return nb ? z1[idx] : z0[idx];
}

template<bool F16IN>
__global__ __launch_bounds__(512, 2)
void mlp_k2(const void* attv, const ushort* __restrict__ Wfg,
            const float* __restrict__ lns, const float* __restrict__ lnb,
            const float* __restrict__ w_out, const float* __restrict__ b_out,
            float* x0_out, float* __restrict__ out1) {
  __shared__ __align__(16) ushort wt[4 * 64 * 88];
  __shared__ __align__(16) ushort act[8][32 * 88];
  __shared__ __align__(16) ushort kpat[16];
  const int tid = threadIdx.x;
  const int lane = tid & 63, wid = tid >> 6;
  const int l31 = lane & 31, lh = lane >> 5;

  for (int idx = tid; idx < 4 * 64 * 10; idx += 512) {
    const int row = idx / 10, q = idx - row * 10;
    *reinterpret_cast<uint4*>(&wt[row * 88 + q * 8]) =
        *reinterpret_cast<const uint4*>(&Wfg[(size_t)row * 80 + q * 8]);
  }
  for (int idx = tid; idx < 256; idx += 512) {
    ushort* rp = &act[idx >> 5][(idx & 31) * 88];
    for (int q = 64; q < 88; ++q) rp[q] = 0;
    rp[64] = 0x3C00;
  }
  if (tid < 16) kpat[tid] = (tid == 0) ? (ushort)0x3C00 : (ushort)0;

  float sc3[2][4][4], lb3[2][4][4], wo3[2][4][4];
  #pragma unroll
  for (int nb = 0; nb < 2; ++nb)
    #pragma unroll
    for (int hi = 0; hi < 4; ++hi)
      #pragma unroll
      for (int j = 0; j < 4; ++j) {
        const int ch = nb * 32 + hi * 8 + lh * 4 + j;
        sc3[nb][hi][j] = lns[192 + ch];
        lb3[nb][hi][j] = lnb[192 + ch];
        wo3[nb][hi][j] = w_out[ch];
      }
  const float b0s = b_out[0];
  __syncthreads();

  ushort* const myact = act[wid];

  for (int it = 0; it < 9; ++it) {
    const int px = ((it * 256 + (int)blockIdx.x) * 8 + wid) * 32 + l31;

    half8 bfr[5];
    if (F16IN) {
      const ushort* ap = (const ushort*)attv + ((size_t)px << 6) + lh * 8;
      #pragma unroll
      for (int g = 0; g < 4; ++g)
        bfr[g] = *reinterpret_cast<const half8*>(ap + g * 16);
    } else {
      const float* ap = (const float*)attv + ((size_t)px << 6) + lh * 8;
      #pragma unroll
      for (int g = 0; g < 4; ++g) {
        const float4 fa = *reinterpret_cast<const float4*>(ap + g * 16);
        const float4 fb = *reinterpret_cast<const float4*>(ap + g * 16 + 4);
        half8 h;
        h[0]=(_Float16)fa.x; h[1]=(_Float16)fa.y; h[2]=(_Float16)fa.z; h[3]=(_Float16)fa.w;
        h[4]=(_Float16)fb.x; h[5]=(_Float16)fb.y; h[6]=(_Float16)fb.z; h[7]=(_Float16)fb.w;
        bfr[g] = h;
      }
    }
    bfr[4] = *reinterpret_cast<const half8*>(&kpat[lh * 8]);

    f32x16 z0, z1;
    float mu = 0.f, rstd = 1.f;
    #pragma unroll
    for (int L = 0; L < 4; ++L) {
      if (L > 0) {
        #pragma unroll
        for (int g = 0; g < 5; ++g)
          bfr[g] = *reinterpret_cast<const half8*>(&myact[l31 * 88 + g * 16 + lh * 8]);
      }
      z0 = (f32x16){0,0,0,0,0,0,0,0,0,0,0,0,0,0,0,0};
      z1 = (f32x16){0,0,0,0,0,0,0,0,0,0,0,0,0,0,0,0};
      #pragma unroll
      for (int g = 0; g < 5; ++g) {
        const half8 a0 = *reinterpret_cast<const half8*>(&wt[(L * 64      + l31) * 88 + g * 16 + lh * 8]);
        const half8 a1 = *reinterpret_cast<const half8*>(&wt[(L * 64 + 32 + l31) * 88 + g * 16 + lh * 8]);
        z0 = __builtin_amdgcn_mfma_f32_32x32x16_f16(a0, bfr[g], z0, 0, 0, 0);
        z1 = __builtin_amdgcn_mfma_f32_32x32x16_f16(a1, bfr[g], z1, 0, 0, 0);
      }
      float sp[4] = {0.f, 0.f, 0.f, 0.f}, qp[4] = {0.f, 0.f, 0.f, 0.f};
      #pragma unroll
      for (int r = 0; r < 16; ++r) {
        const float v0 = fmaxf(z0[r], 0.f); z0[r] = v0;
        const float v1 = fmaxf(z1[r], 0.f); z1[r] = v1;
        sp[r & 3] += v0 + v1;
        qp[r & 3] += v0 * v0 + v1 * v1;
      }
      float s = (sp[0] + sp[1]) + (sp[2] + sp[3]);
      float qq = (qp[0] + qp[1]) + (qp[2] + qp[3]);
      s  += __shfl_xor(s, 32, 64);
      qq += __shfl_xor(qq, 32, 64);
      mu = s * 0.015625f;
      const float var = qq * 0.015625f - mu * mu;
      rstd = rsqrtf(var + 1e-6f);
      if (L < 3) {
        #pragma unroll
        for (int nb = 0; nb < 2; ++nb)
          #pragma unroll
          for (int hi = 0; hi < 4; ++hi) {
            ushort4 pk;
            pk.x = f2h(rstd * zsel(z0, z1, nb, hi * 4 + 0));
            pk.y = f2h(rstd * zsel(z0, z1, nb, hi * 4 + 1));
            pk.z = f2h(rstd * zsel(z0, z1, nb, hi * 4 + 2));
            pk.w = f2h(rstd * zsel(z0, z1, nb, hi * 4 + 3));
            *reinterpret_cast<ushort4*>(&myact[l31 * 88 + nb * 32 + hi * 8 + lh * 4]) = pk;
          }
        if (lh == 0) myact[l31 * 88 + 65] = f2h(-(mu * rstd));
      }
    }

    const float t = mu * rstd;
    float part0 = 0.f, part1 = 0.f;
    #pragma unroll
    for (int nb = 0; nb < 2; ++nb)
      #pragma unroll
      for (int hi = 0; hi < 4; ++hi) {
        f32x4 yv;
        #pragma unroll
        for (int j = 0; j < 4; ++j) {
          const float v = zsel(z0, z1, nb, hi * 4 + j);
          const float y = v * (rstd * sc3[nb][hi][j]) + (lb3[nb][hi][j] - t * sc3[nb][hi][j]);
          yv[j] = y;
          if (j & 1) part1 += y * wo3[nb][hi][j];
          else       part0 += y * wo3[nb][hi][j];
        }
        *reinterpret_cast<f32x4*>(&x0_out[((size_t)px << 6) + nb * 32 + hi * 8 + lh * 4]) = yv;
      }
    float part = part0 + part1;
    part += __shfl_xor(part, 32, 64);
    if (lh == 0) out1[px] = part + b0s;
  }
}

extern "C" void kernel_launch(void* const* d_in, const int* in_sizes, int n_in,
                              void* d_out, int out_size, void* d_ws, size_t ws_size,
                              hipStream_t stream) {
  const float* x     = (const float*)d_in[0];
  const float* Ws    = (const float*)d_in[1];
  const float* bs    = (const float*)d_in[2];
  const float* lns   = (const float*)d_in[3];
  const float* lnbv  = (const float*)d_in[4];
  const float* w_out = (const float*)d_in[5];
  const float* b_out = (const float*)d_in[6];
  float* x0_out = (float*)d_out;
  float* out1   = x0_out + (size_t)HWPX * 64;

  const size_t attBytes = (size_t)HWPX * 64 * sizeof(ushort);   // 75.5 MB
  if (ws_size >= attBytes + 65536) {
    ushort* atth = (ushort*)d_ws;
    ushort* Wfg  = (ushort*)((char*)d_ws + attBytes);
    prep_wf<<<1, 256, 0, stream>>>(Ws, bs, lns, lnbv, Wfg);
    att_k1<true><<<512, 512, 0, stream>>>(x, atth);
    mlp_k2<true><<<256, 512, 0, stream>>>(atth, Wfg, lns, lnbv,
                                          w_out, b_out, x0_out, out1);
  } else {
    ushort* Wfg = (ushort*)d_ws;
    prep_wf<<<1, 256, 0, stream>>>(Ws, bs, lns, lnbv, Wfg);
    att_k1<false><<<512, 512, 0, stream>>>(x, d_out);
    mlp_k2<false><<<256, 512, 0, stream>>>(d_out, Wfg, lns, lnbv,
                                           w_out, b_out, x0_out, out1);
  }
}